// Round 3
// baseline (193.282 us; speedup 1.0000x reference)
//
#include <hip/hip_runtime.h>

// ---------------- problem constants ----------------
#define DIMC 1024
#define NH   16
#define HD   64
#define BSZ  2
#define TSZ  2048
#define MROWS (BSZ*TSZ)   // 4096

typedef __attribute__((ext_vector_type(8))) short s16x8;   // 8 bf16 (4 VGPRs)
typedef __attribute__((ext_vector_type(4))) float f32x4;   // 4 fp32

__device__ __forceinline__ float b2f(unsigned short u) {
  return __uint_as_float(((unsigned)u) << 16);
}
__device__ __forceinline__ unsigned short f2b(float f) {
  unsigned x = __float_as_uint(f);
  unsigned r = x + 0x7fffu + ((x >> 16) & 1u);   // RTNE
  return (unsigned short)(r >> 16);
}
// single-instruction packed f32->bf16 (RTNE), lo = a, hi = b  [T12 recipe]
__device__ __forceinline__ unsigned pk2(float a, float b) {
  unsigned r;
  asm("v_cvt_pk_bf16_f32 %0, %1, %2" : "=v"(r) : "v"(a), "v"(b));
  return r;
}
// 2^x in one v_exp_f32 (softmax runs in log2 domain)
__device__ __forceinline__ float ex2(float x) {
#if __has_builtin(__builtin_amdgcn_exp2f)
  return __builtin_amdgcn_exp2f(x);
#else
  float r; asm("v_exp_f32 %0, %1" : "=v"(r) : "v"(x)); return r;
#endif
}
__device__ __forceinline__ float ldsc(const void* __restrict__ p, int idx, int isf32) {
  return isf32 ? ((const float*)p)[idx] : b2f(((const unsigned short*)p)[idx]);
}

// 16-byte global -> LDS DMA. lds base wave-uniform; HW writes lane i at base+16i.
__device__ __forceinline__ void async_cp16(const unsigned short* g, unsigned short* l) {
  __builtin_amdgcn_global_load_lds(
      (const __attribute__((address_space(1))) unsigned int*)g,
      (__attribute__((address_space(3))) unsigned int*)l, 16, 0, 0);
}

// ---------------------------------------------------------------------------
__global__ void detect_dtype(const unsigned short* __restrict__ cosp, int* __restrict__ flag) {
  const int i = threadIdx.x;   // 64 threads
  const unsigned long long m = __ballot(cosp[i] >= 0x4000u);
  if (i == 0) *flag = (m != 0ull) ? 1 : 0;
}

// ---------------------------------------------------------------------------
// One-shot fp32 -> bf16 conversion of x, w_qkv, w_out (only when inputs fp32).
// ---------------------------------------------------------------------------
__global__ __launch_bounds__(256)
void cvt_all(const float* __restrict__ x, const float* __restrict__ wq,
             const float* __restrict__ wo,
             unsigned short* __restrict__ xb, unsigned short* __restrict__ wqb,
             unsigned short* __restrict__ wob, const int* __restrict__ flag) {
  if (*flag == 0) return;
  const unsigned id = blockIdx.x * 256 + threadIdx.x;  // 0..1048575
  const float* src; unsigned short* dst; unsigned off;
  if (id < 524288u) { src = x; dst = xb; off = id; }
  else if (id < 917504u) { src = wq; dst = wqb; off = id - 524288u; }
  else { src = wo; dst = wob; off = id - 917504u; }
  const float4 a = ((const float4*)src)[off * 2];
  const float4 b = ((const float4*)src)[off * 2 + 1];
  uint4 u;
  u.x = pk2(a.x, a.y); u.y = pk2(a.z, a.w);
  u.z = pk2(b.x, b.y); u.w = pk2(b.z, b.w);
  ((uint4*)dst)[off] = u;
}

// ---------------------------------------------------------------------------
// QKV projection GEMM, 128x128 tile (m93/m97 ladder step: 2x MFMA density
// per staged byte vs the 128x64 tile). BK=64, K=1024, 256 threads, 4 waves;
// wave w owns rows wm=w*32 (2 i-tiles) x all 128 cols (8 j-tiles) ->
// acc[2][8] (64 AGPR). Grid (24, 32) = 768 blocks -> 3 blocks/CU. LDS 32 KB
// (A 128x64 + B 128x64), XOR pre-swizzled source chunks, linear LDS.
// Tile spans exactly 2 heads; never crosses a q/k/v boundary (1024%128==0).
// Epilogue: RoPE (q pre-scaled by 0.125*log2e), per-wave 32x128 LDS
// transpose tile (exactly reuses the 32 KB), coalesced uint4 scatter into
// q/k/v [B,H,T,64] bf16.
// ---------------------------------------------------------------------------
__global__ __launch_bounds__(256)
void gemm_qkv128(const void* __restrict__ Aorig, const unsigned short* __restrict__ Aconv,
                 const void* __restrict__ Worig, const unsigned short* __restrict__ Wconv,
                 const void* __restrict__ cosp, const void* __restrict__ sinp,
                 unsigned short* __restrict__ qout,
                 unsigned short* __restrict__ kout,
                 unsigned short* __restrict__ vout,
                 const int* __restrict__ dflag) {
  const int f32flag = *dflag;
  const unsigned short* A = f32flag ? Aconv : (const unsigned short*)Aorig;
  const unsigned short* W = f32flag ? Wconv : (const unsigned short*)Worig;

  const int tid = threadIdx.x;
  const int m0 = blockIdx.y * 128;
  const int n0 = blockIdx.x * 128;

  __shared__ __align__(16) unsigned short s_ab[2 * 128 * 64];  // 32 KB
  unsigned short* s_a = s_ab;
  unsigned short* s_b = s_ab + 128 * 64;

  const int lane = tid & 63;
  const int wave = tid >> 6;
  const int wm = wave * 32;                // wave's M offset (32 rows)
  const int m16 = lane & 15;
  const int quad = lane >> 4;

  const int srow = lane >> 3;
  const int schunk = (lane & 7) ^ srow;

  f32x4 acc[2][8];
#pragma unroll
  for (int i = 0; i < 2; ++i)
#pragma unroll
    for (int j = 0; j < 8; ++j) acc[i][j] = (f32x4){0.f, 0.f, 0.f, 0.f};

  for (int kt = 0; kt < DIMC; kt += 64) {
    __syncthreads();
#pragma unroll
    for (int u = 0; u < 4; ++u) {          // A and B: 128 rows each
      const int r0 = u * 32 + wave * 8;
      async_cp16(A + (size_t)(m0 + r0 + srow) * DIMC + kt + schunk * 8, &s_a[r0 * 64]);
      async_cp16(W + (size_t)(n0 + r0 + srow) * DIMC + kt + schunk * 8, &s_b[r0 * 64]);
    }
    __syncthreads();
#pragma unroll
    for (int kk = 0; kk < 64; kk += 32) {
      const int cx = ((kk >> 3) + quad) ^ (m16 & 7);
      s16x8 af[2], bf[8];
#pragma unroll
      for (int i = 0; i < 2; ++i)
        af[i] = *(const s16x8*)&s_a[(wm + i * 16 + m16) * 64 + cx * 8];
#pragma unroll
      for (int j = 0; j < 8; ++j)
        bf[j] = *(const s16x8*)&s_b[(j * 16 + m16) * 64 + cx * 8];
#pragma unroll
      for (int i = 0; i < 2; ++i)
#pragma unroll
        for (int j = 0; j < 8; ++j)
          acc[i][j] = __builtin_amdgcn_mfma_f32_16x16x32_bf16(af[i], bf[j], acc[i][j], 0, 0, 0);
    }
  }

  // Epilogue. C/D layout: col = lane&15 (within tile j), row = quad*4 + reg.
  const int sel = n0 >> 10;                // 0=q 1=k 2=v (block-uniform)
  const int h0 = (n0 & 1023) >> 6;         // first of the two heads in tile
  unsigned short* dst = (sel == 0) ? qout : ((sel == 1) ? kout : vout);
  // q pre-scaled by 1/sqrt(64) * log2(e) so attention softmax is pure exp2
  const float qsc = (sel == 0) ? 0.18033688f : 1.0f;
  __syncthreads();                         // s_ab dead; reuse as transpose tile
  unsigned short* tile = s_ab + wave * 4096;   // 32x128 u16 per wave (8 KB)
  if (sel < 2) {                           // q/k: RoPE in-register
#pragma unroll
    for (int i = 0; i < 2; ++i)
#pragma unroll
      for (int r = 0; r < 4; ++r) {
        const int row_l = i * 16 + quad * 4 + r;          // 0..31
        const int t = (m0 + wm + row_l) & 2047;
#pragma unroll
        for (int hh = 0; hh < 2; ++hh)
#pragma unroll
          for (int jg = 0; jg < 2; ++jg) {
            const int d = jg * 16 + m16;   // head-local 0..31
            const float c = ldsc(cosp, t * 32 + d, f32flag);
            const float sn = ldsc(sinp, t * 32 + d, f32flag);
            const float v1 = acc[i][hh * 4 + jg][r];
            const float v2 = acc[i][hh * 4 + jg + 2][r];
            tile[row_l * 128 + hh * 64 + d]      = f2b((v1 * c - v2 * sn) * qsc);
            tile[row_l * 128 + hh * 64 + d + 32] = f2b((v1 * sn + v2 * c) * qsc);
          }
      }
  } else {
#pragma unroll
    for (int i = 0; i < 2; ++i)
#pragma unroll
      for (int r = 0; r < 4; ++r) {
        const int row_l = i * 16 + quad * 4 + r;
#pragma unroll
        for (int j = 0; j < 8; ++j)
          tile[row_l * 128 + j * 16 + m16] = f2b(acc[i][j][r]);
      }
  }
  // wave-private read-back: 8 coalesced uint4 stores per lane (2 heads x 4)
#pragma unroll
  for (int s = 0; s < 4; ++s) {
    const int row_l = s * 8 + (lane >> 3);
    const int seg = lane & 7;
    const int mrow_ = m0 + wm + row_l;
    const int bb = mrow_ >> 11;
    const int t = mrow_ & 2047;
#pragma unroll
    for (int hh = 0; hh < 2; ++hh) {
      unsigned short* drow = dst + (((size_t)(bb * NH + h0 + hh)) * TSZ + t) * HD;
      *(uint4*)(drow + seg * 8) = *(const uint4*)&tile[row_l * 128 + hh * 64 + seg * 8];
    }
  }
}

// ---------------------------------------------------------------------------
// MFMA bf16 GEMM (async staging):  C[M,N] = A[M,K] @ W[N,K]^T, bf16 operands.
// M-tile 128, N-tile 64, BK=64, K=1024. 256 threads; wave w owns rows
// wm=w*32 (2 i-tiles) x all 64 cols (4 j-tiles) -> acc[2][4] (32 AGPR).
// Used for the out-projection only (512 blocks -> 2/CU).
// ---------------------------------------------------------------------------
template <int EPI>
__global__ __launch_bounds__(256)
void gemm_bt_async(const void* __restrict__ Aorig, const unsigned short* __restrict__ Aconv,
                   const void* __restrict__ Worig, const unsigned short* __restrict__ Wconv,
                   void* __restrict__ C,
                   const int* __restrict__ dflag, int Nsz) {
  const int f32flag = *dflag;
  const unsigned short* A = f32flag ? Aconv : (const unsigned short*)Aorig;
  const unsigned short* W = f32flag ? Wconv : (const unsigned short*)Worig;

  const int tid = threadIdx.x;
  const int m0 = blockIdx.y * 128;
  const int n0 = blockIdx.x * 64;

  __shared__ __align__(16) unsigned short s_ab[128 * 64 + 64 * 64];  // 24 KB
  unsigned short* s_a = s_ab;
  unsigned short* s_b = s_ab + 128 * 64;

  const int lane = tid & 63;
  const int wave = tid >> 6;
  const int wm = wave * 32;                // wave's M offset (32 rows)
  const int m16 = lane & 15;
  const int quad = lane >> 4;

  const int srow = lane >> 3;
  const int schunk = (lane & 7) ^ srow;

  f32x4 acc[2][4];
#pragma unroll
  for (int i = 0; i < 2; ++i)
#pragma unroll
    for (int j = 0; j < 4; ++j) acc[i][j] = (f32x4){0.f, 0.f, 0.f, 0.f};

  for (int kt = 0; kt < DIMC; kt += 64) {
    __syncthreads();
#pragma unroll
    for (int u = 0; u < 4; ++u) {          // A: 128 rows
      const int r0 = u * 32 + wave * 8;
      async_cp16(A + (size_t)(m0 + r0 + srow) * DIMC + kt + schunk * 8, &s_a[r0 * 64]);
    }
#pragma unroll
    for (int u = 0; u < 2; ++u) {          // B: 64 rows
      const int r0 = u * 32 + wave * 8;
      async_cp16(W + (size_t)(n0 + r0 + srow) * DIMC + kt + schunk * 8, &s_b[r0 * 64]);
    }
    __syncthreads();
#pragma unroll
    for (int kk = 0; kk < 64; kk += 32) {
      const int cx = ((kk >> 3) + quad) ^ (m16 & 7);
      s16x8 af[2], bf[4];
#pragma unroll
      for (int i = 0; i < 2; ++i)
        af[i] = *(const s16x8*)&s_a[(wm + i * 16 + m16) * 64 + cx * 8];
#pragma unroll
      for (int j = 0; j < 4; ++j)
        bf[j] = *(const s16x8*)&s_b[(j * 16 + m16) * 64 + cx * 8];
#pragma unroll
      for (int i = 0; i < 2; ++i)
#pragma unroll
        for (int j = 0; j < 4; ++j)
          acc[i][j] = __builtin_amdgcn_mfma_f32_16x16x32_bf16(af[i], bf[j], acc[i][j], 0, 0, 0);
    }
  }

  // Epilogue. C/D layout: col = lane&15 (tile j), row = quad*4 + reg.
  if (f32flag) {
    float* Cf = (float*)C;
#pragma unroll
    for (int i = 0; i < 2; ++i)
#pragma unroll
      for (int j = 0; j < 4; ++j)
#pragma unroll
        for (int r = 0; r < 4; ++r) {
          const int mrow_ = m0 + wm + i * 16 + quad * 4 + r;
          const int col = n0 + j * 16 + m16;
          Cf[(size_t)mrow_ * Nsz + col] = acc[i][j][r];
        }
  } else {
    unsigned short* Ch = (unsigned short*)C;
#pragma unroll
    for (int i = 0; i < 2; ++i)
#pragma unroll
      for (int j = 0; j < 4; ++j)
#pragma unroll
        for (int r = 0; r < 4; ++r) {
          const int mrow_ = m0 + wm + i * 16 + quad * 4 + r;
          const int col = n0 + j * 16 + m16;
          Ch[(size_t)mrow_ * Nsz + col] = f2b(acc[i][j][r]);
        }
  }
}

// ---------------------------------------------------------------------------
// MFMA flash attention, S^T form, 512 threads (8 waves).
// Front/back subtile fusion: each block owns TWO 64-row q-subtiles of one
// (b,h) — waves 0-3 handle front subtile p, waves 4-7 the mirrored back
// subtile 31-p. Both consume the SAME KV chunk stream; every block does
// exactly 132 active wave-chunks. Co-resident pairs (c, c+256): duration
// sum 49, constant. Softmax in log2 domain (q pre-scaled by log2e),
// defer-max (THR=8), v_cvt_pk_bf16_f32 packing, setprio around MFMA
// clusters. Double-buffered K/V LDS: one barrier per chunk.
// ---------------------------------------------------------------------------
__device__ __forceinline__ void attn_pass(
    const unsigned short* __restrict__ qgh, const unsigned short* __restrict__ kgh,
    const unsigned short* __restrict__ vgh, unsigned short* __restrict__ outg,
    int b, int h, int qs, int nc, unsigned short* s_k0, unsigned short* s_k1,
    unsigned short* s_v0, unsigned short* s_v1, unsigned short* s_p,
    int tid, int lane, int w, int m16, int quad) {
  const unsigned short* qrow = qgh + (size_t)(qs + m16) * HD;
  const s16x8 bq0 = *(const s16x8*)(qrow + quad * 8);
  const s16x8 bq1 = *(const s16x8*)(qrow + 32 + quad * 8);

  f32x4 oacc[4];
#pragma unroll
  for (int dt = 0; dt < 4; ++dt) oacc[dt] = (f32x4){0.f, 0.f, 0.f, 0.f};
  float m_ = -1e30f, l_ = 0.f;

  const int krow = tid >> 3, kseg = tid & 7;   // 64 rows x 8 segs
  const int vkey = tid & 63, vseg = tid >> 6;  // 64 keys x 8 dsegs

  {  // prologue: chunk 0 into buf0
    const uint4 pk = *(const uint4*)(kgh + (size_t)krow * HD + kseg * 8);
    const uint4 pv = *(const uint4*)(vgh + (size_t)vkey * HD + vseg * 8);
    *(uint4*)&s_k0[krow * 72 + kseg * 8] = pk;
    const unsigned short* vv = (const unsigned short*)&pv;
#pragma unroll
    for (int jj = 0; jj < 8; ++jj) s_v0[(vseg * 8 + jj) * 72 + vkey] = vv[jj];
  }

  for (int kc = 0; kc < nc; ++kc) {
    unsigned short* sk = (kc & 1) ? s_k1 : s_k0;
    unsigned short* sv = (kc & 1) ? s_v1 : s_v0;
    unsigned short* skN = (kc & 1) ? s_k0 : s_k1;
    unsigned short* svN = (kc & 1) ? s_v0 : s_v1;
    __syncthreads();                       // buf[kc] ready; buf[kc+1] free
    uint4 pk, pv;
    const int pf = (kc + 1 < nc);
    if (pf) {                              // prefetch next chunk (overlaps compute)
      pk = *(const uint4*)(kgh + (size_t)((kc + 1) * 64 + krow) * HD + kseg * 8);
      pv = *(const uint4*)(vgh + (size_t)((kc + 1) * 64 + vkey) * HD + vseg * 8);
    }

    if (kc * 64 <= qs + 15) {              // not fully masked for this wave
      f32x4 sacc[4];
#pragma unroll
      for (int jt = 0; jt < 4; ++jt) sacc[jt] = (f32x4){0.f, 0.f, 0.f, 0.f};
      __builtin_amdgcn_s_setprio(1);
#pragma unroll
      for (int jt = 0; jt < 4; ++jt) {
        const s16x8 ak0 = *(const s16x8*)&sk[(jt * 16 + m16) * 72 + quad * 8];
        sacc[jt] = __builtin_amdgcn_mfma_f32_16x16x32_bf16(ak0, bq0, sacc[jt], 0, 0, 0);
        const s16x8 ak1 = *(const s16x8*)&sk[(jt * 16 + m16) * 72 + 32 + quad * 8];
        sacc[jt] = __builtin_amdgcn_mfma_f32_16x16x32_bf16(ak1, bq1, sacc[jt], 0, 0, 0);
      }
      __builtin_amdgcn_s_setprio(0);

      if (kc * 64 + 63 > qs) {             // diagonal region: element mask
#pragma unroll
        for (int jt = 0; jt < 4; ++jt)
#pragma unroll
          for (int r = 0; r < 4; ++r)
            if (kc * 64 + jt * 16 + quad * 4 + r > qs + m16) sacc[jt][r] = -1e30f;
      }

      // per-query tile max (scores are log2-scaled)
      float mx = sacc[0][0];
#pragma unroll
      for (int jt = 0; jt < 4; ++jt)
#pragma unroll
        for (int r = 0; r < 4; ++r) mx = fmaxf(mx, sacc[jt][r]);
      mx = fmaxf(mx, __shfl_xor(mx, 16, 64));
      mx = fmaxf(mx, __shfl_xor(mx, 32, 64));
      // defer-max: only rescale when the running max grew by > THR=8
      // (P bounded by 2^8=256; fp32 accumulation unaffected)
      if (!__all(mx <= m_ + 8.0f)) {
        const float mn = fmaxf(m_, mx);
        const float alpha = ex2(m_ - mn);
        m_ = mn;
        l_ *= alpha;
#pragma unroll
        for (int dt = 0; dt < 4; ++dt)
#pragma unroll
          for (int r = 0; r < 4; ++r) oacc[dt][r] *= alpha;
      }
      float rs = 0.f;
#pragma unroll
      for (int jt = 0; jt < 4; ++jt)
#pragma unroll
        for (int r = 0; r < 4; ++r) {
          const float p = ex2(sacc[jt][r] - m_);
          sacc[jt][r] = p;
          rs += p;
        }
      rs += __shfl_xor(rs, 16, 64);
      rs += __shfl_xor(rs, 32, 64);
      l_ += rs;

#pragma unroll
      for (int jt = 0; jt < 4; ++jt) {
        uint2 pw;
        pw.x = pk2(sacc[jt][0], sacc[jt][1]);
        pw.y = pk2(sacc[jt][2], sacc[jt][3]);
        *(uint2*)&s_p[(w * 16 + m16) * 72 + jt * 16 + quad * 4] = pw;
      }

      __builtin_amdgcn_s_setprio(1);
#pragma unroll
      for (int kk = 0; kk < 64; kk += 32) {
        const s16x8 bp = *(const s16x8*)&s_p[(w * 16 + m16) * 72 + kk + quad * 8];
#pragma unroll
        for (int dt = 0; dt < 4; ++dt) {
          const s16x8 av = *(const s16x8*)&sv[(dt * 16 + m16) * 72 + kk + quad * 8];
          oacc[dt] = __builtin_amdgcn_mfma_f32_16x16x32_bf16(av, bp, oacc[dt], 0, 0, 0);
        }
      }
      __builtin_amdgcn_s_setprio(0);
    }

    if (pf) {                              // store next chunk into other buffer
      *(uint4*)&skN[krow * 72 + kseg * 8] = pk;
      const unsigned short* vv = (const unsigned short*)&pv;
#pragma unroll
      for (int jj = 0; jj < 8; ++jj) svN[(vseg * 8 + jj) * 72 + vkey] = vv[jj];
    }
  }

  // epilogue: normalize, transpose via wave-private s_p rows, coalesced store
  const float linv = 1.0f / l_;
#pragma unroll
  for (int dt = 0; dt < 4; ++dt) {
    uint2 ow;
    ow.x = pk2(oacc[dt][0] * linv, oacc[dt][1] * linv);
    ow.y = pk2(oacc[dt][2] * linv, oacc[dt][3] * linv);
    *(uint2*)&s_p[(w * 16 + m16) * 72 + dt * 16 + quad * 4] = ow;
  }
  {
    const int qq = lane >> 2, dseg = lane & 3;   // wave-private rows: no barrier
    const uint4 o0 = *(const uint4*)&s_p[(w * 16 + qq) * 72 + dseg * 16];
    const uint4 o1 = *(const uint4*)&s_p[(w * 16 + qq) * 72 + dseg * 16 + 8];
    unsigned short* orow =
        outg + ((size_t)b * TSZ + qs + qq) * DIMC + h * 64 + dseg * 16;
    *(uint4*)orow = o0;
    *(uint4*)(orow + 8) = o1;
  }
}

__global__ __launch_bounds__(512)
void attn_fwd_mfma(const unsigned short* __restrict__ qg,
                   const unsigned short* __restrict__ kg,
                   const unsigned short* __restrict__ vg,
                   unsigned short* __restrict__ outg) {
  const int tid = threadIdx.x;
  const int lane = tid & 63;
  const int w = tid >> 6;                // wave 0..7
  const int m16 = lane & 15;
  const int quad = lane >> 4;
  const int l = (int)blockIdx.x;         // 0..511
  // Pair id p: l<256 -> p = g (nc=32-g, long, dispatched first);
  // l>=256 -> p = 15-g (nc=17+g, short). Co-resident pair (c, c+256):
  // durations (32-g)+(17+g) = 49, constant for every CU.
  const int g = (l & 255) >> 5;          // 0..7
  const int p = (l < 256) ? g : (15 - g);
  const int nc = 32 - p;                 // KV chunks for the back subtile
  const int bh = l & 31;
  const int b = bh >> 4, h = bh & 15;
  const size_t base = (size_t)bh * TSZ * HD;
  // waves 0-3: front subtile p; waves 4-7: back subtile 31-p
  const int sub = (w < 4) ? p : (31 - p);
  const int qs = sub * 64 + (w & 3) * 16;   // wave's first query row

  __shared__ __align__(16) unsigned short s_k0[64 * 72];
  __shared__ __align__(16) unsigned short s_k1[64 * 72];
  __shared__ __align__(16) unsigned short s_v0[64 * 72];
  __shared__ __align__(16) unsigned short s_v1[64 * 72];
  __shared__ __align__(16) unsigned short s_p[128 * 72];

  attn_pass(qg + base, kg + base, vg + base, outg, b, h, qs, nc,
            s_k0, s_k1, s_v0, s_v1, s_p, tid, lane, w, m16, quad);
}

// ---------------------------------------------------------------------------
extern "C" void kernel_launch(void* const* d_in, const int* in_sizes, int n_in,
                              void* d_out, int out_size, void* d_ws, size_t ws_size,
                              hipStream_t stream) {
  (void)in_sizes; (void)n_in; (void)out_size; (void)ws_size;
  const void* x    = d_in[0];
  const void* cosp = d_in[1];
  const void* sinp = d_in[2];
  const void* wqkv = d_in[3];
  const void* wout = d_in[4];

  int* dflag = (int*)d_ws;
  const size_t per = (size_t)BSZ * NH * TSZ * HD;       // 4,194,304 elems
  unsigned short* q = (unsigned short*)((char*)d_ws + 256);
  unsigned short* k = q + per;
  unsigned short* v = k + per;
  unsigned short* attnb = v + per;                      // [B,T,DIM] bf16
  unsigned short* xb   = attnb + (size_t)MROWS * DIMC;  // bf16 copies (fp32 case)
  unsigned short* wqb  = xb + (size_t)MROWS * DIMC;
  unsigned short* wob  = wqb + (size_t)3 * DIMC * DIMC;

  detect_dtype<<<1, 64, 0, stream>>>((const unsigned short*)cosp, dflag);
  cvt_all<<<dim3(4096), dim3(256), 0, stream>>>(
      (const float*)x, (const float*)wqkv, (const float*)wout, xb, wqb, wob, dflag);
  // QKV projection: 128x128 tiles -> 768 blocks (3/CU co-residency)
  gemm_qkv128<<<dim3(3 * DIMC / 128, MROWS / 128), dim3(256), 0, stream>>>(
      x, xb, wqkv, wqb, cosp, sinp, q, k, v, dflag);
  // causal flash attention: 512 front/back-fused blocks, balanced durations
  attn_fwd_mfma<<<dim3(512), dim3(512), 0, stream>>>(q, k, v, attnb);
  // out-projection: 128x64 tiles -> 512 blocks
  gemm_bt_async<0><<<dim3(DIMC / 64, MROWS / 128), dim3(256), 0, stream>>>(
      attnb, attnb, wout, wob, d_out, dflag, DIMC);
}

// Round 4
// 182.994 us; speedup vs baseline: 1.0562x; 1.0562x over previous
//
#include <hip/hip_runtime.h>

// ---------------- problem constants ----------------
#define DIMC 1024
#define NH   16
#define HD   64
#define BSZ  2
#define TSZ  2048
#define MROWS (BSZ*TSZ)   // 4096

typedef __attribute__((ext_vector_type(8))) short s16x8;   // 8 bf16 (4 VGPRs)
typedef __attribute__((ext_vector_type(4))) float f32x4;   // 4 fp32

__device__ __forceinline__ float b2f(unsigned short u) {
  return __uint_as_float(((unsigned)u) << 16);
}
__device__ __forceinline__ unsigned short f2b(float f) {
  unsigned x = __float_as_uint(f);
  unsigned r = x + 0x7fffu + ((x >> 16) & 1u);   // RTNE
  return (unsigned short)(r >> 16);
}
// single-instruction packed f32->bf16 (RTNE), lo = a, hi = b  [T12 recipe]
__device__ __forceinline__ unsigned pk2(float a, float b) {
  unsigned r;
  asm("v_cvt_pk_bf16_f32 %0, %1, %2" : "=v"(r) : "v"(a), "v"(b));
  return r;
}
// 2^x in one v_exp_f32 (softmax runs in log2 domain)
__device__ __forceinline__ float ex2(float x) {
#if __has_builtin(__builtin_amdgcn_exp2f)
  return __builtin_amdgcn_exp2f(x);
#else
  float r; asm("v_exp_f32 %0, %1" : "=v"(r) : "v"(x)); return r;
#endif
}
__device__ __forceinline__ float ldsc(const void* __restrict__ p, int idx, int isf32) {
  return isf32 ? ((const float*)p)[idx] : b2f(((const unsigned short*)p)[idx]);
}

// 16-byte global -> LDS DMA. lds base wave-uniform; HW writes lane i at base+16i.
__device__ __forceinline__ void async_cp16(const unsigned short* g, unsigned short* l) {
  __builtin_amdgcn_global_load_lds(
      (const __attribute__((address_space(1))) unsigned int*)g,
      (__attribute__((address_space(3))) unsigned int*)l, 16, 0, 0);
}

// ---------------------------------------------------------------------------
__global__ void detect_dtype(const unsigned short* __restrict__ cosp, int* __restrict__ flag) {
  const int i = threadIdx.x;   // 64 threads
  const unsigned long long m = __ballot(cosp[i] >= 0x4000u);
  if (i == 0) *flag = (m != 0ull) ? 1 : 0;
}

// ---------------------------------------------------------------------------
// One-shot fp32 -> bf16 conversion of x, w_qkv, w_out (only when inputs fp32).
// ---------------------------------------------------------------------------
__global__ __launch_bounds__(256)
void cvt_all(const float* __restrict__ x, const float* __restrict__ wq,
             const float* __restrict__ wo,
             unsigned short* __restrict__ xb, unsigned short* __restrict__ wqb,
             unsigned short* __restrict__ wob, const int* __restrict__ flag) {
  if (*flag == 0) return;
  const unsigned id = blockIdx.x * 256 + threadIdx.x;  // 0..1048575
  const float* src; unsigned short* dst; unsigned off;
  if (id < 524288u) { src = x; dst = xb; off = id; }
  else if (id < 917504u) { src = wq; dst = wqb; off = id - 524288u; }
  else { src = wo; dst = wob; off = id - 917504u; }
  const float4 a = ((const float4*)src)[off * 2];
  const float4 b = ((const float4*)src)[off * 2 + 1];
  uint4 u;
  u.x = pk2(a.x, a.y); u.y = pk2(a.z, a.w);
  u.z = pk2(b.x, b.y); u.w = pk2(b.z, b.w);
  ((uint4*)dst)[off] = u;
}

// ---------------------------------------------------------------------------
// QKV projection GEMM, 128x128 tile, 512 threads / 8 waves (4M x 2N wave
// grid). Round-3's 256-thread version died of occupancy (13.5%: acc[2][8] =
// 64 AGPR + 4 waves/block -> ~1 resident block/CU, barrier drains exposed).
// This keeps the 128^2 MFMA density but each wave owns 32x64 -> acc[2][4]
// (32 AGPR), ~90 VGPR total, __launch_bounds__(512,4) -> >=2 resident
// blocks (16 waves/CU). Grid (24, 32) = 768 blocks. LDS 32 KB, XOR
// pre-swizzled source chunks, linear LDS. Per-wave N-range = exactly one
// head, so RoPE epilogue = per-wave 32x64 transpose tile (8 x 4 KB reuses
// the 32 KB exactly), coalesced uint4 scatter into q/k/v [B,H,T,64] bf16.
// ---------------------------------------------------------------------------
__global__ __launch_bounds__(512, 4)
void gemm_qkv128(const void* __restrict__ Aorig, const unsigned short* __restrict__ Aconv,
                 const void* __restrict__ Worig, const unsigned short* __restrict__ Wconv,
                 const void* __restrict__ cosp, const void* __restrict__ sinp,
                 unsigned short* __restrict__ qout,
                 unsigned short* __restrict__ kout,
                 unsigned short* __restrict__ vout,
                 const int* __restrict__ dflag) {
  const int f32flag = *dflag;
  const unsigned short* A = f32flag ? Aconv : (const unsigned short*)Aorig;
  const unsigned short* W = f32flag ? Wconv : (const unsigned short*)Worig;

  const int tid = threadIdx.x;
  const int m0 = blockIdx.y * 128;
  const int n0 = blockIdx.x * 128;

  __shared__ __align__(16) unsigned short s_ab[2 * 128 * 64];  // 32 KB
  unsigned short* s_a = s_ab;
  unsigned short* s_b = s_ab + 128 * 64;

  const int lane = tid & 63;
  const int wave = tid >> 6;               // 0..7
  const int wm = (wave & 3) * 32;          // wave's M offset (32 rows)
  const int wn = (wave >> 2) * 64;         // wave's N offset (64 cols = 1 head)
  const int m16 = lane & 15;
  const int quad = lane >> 4;

  const int srow = lane >> 3;
  const int schunk = (lane & 7) ^ srow;

  f32x4 acc[2][4];
#pragma unroll
  for (int i = 0; i < 2; ++i)
#pragma unroll
    for (int j = 0; j < 4; ++j) acc[i][j] = (f32x4){0.f, 0.f, 0.f, 0.f};

  for (int kt = 0; kt < DIMC; kt += 64) {
    __syncthreads();
#pragma unroll
    for (int u = 0; u < 2; ++u) {          // A and B: 128 rows each, 8 waves
      const int r0 = u * 64 + wave * 8;
      async_cp16(A + (size_t)(m0 + r0 + srow) * DIMC + kt + schunk * 8, &s_a[r0 * 64]);
      async_cp16(W + (size_t)(n0 + r0 + srow) * DIMC + kt + schunk * 8, &s_b[r0 * 64]);
    }
    __syncthreads();
#pragma unroll
    for (int kk = 0; kk < 64; kk += 32) {
      const int cx = ((kk >> 3) + quad) ^ (m16 & 7);
      s16x8 af[2], bf[4];
#pragma unroll
      for (int i = 0; i < 2; ++i)
        af[i] = *(const s16x8*)&s_a[(wm + i * 16 + m16) * 64 + cx * 8];
#pragma unroll
      for (int j = 0; j < 4; ++j)
        bf[j] = *(const s16x8*)&s_b[(wn + j * 16 + m16) * 64 + cx * 8];
#pragma unroll
      for (int i = 0; i < 2; ++i)
#pragma unroll
        for (int j = 0; j < 4; ++j)
          acc[i][j] = __builtin_amdgcn_mfma_f32_16x16x32_bf16(af[i], bf[j], acc[i][j], 0, 0, 0);
    }
  }

  // Epilogue. C/D layout: col = lane&15 (within tile j), row = quad*4 + reg.
  const int sel = n0 >> 10;                // 0=q 1=k 2=v (block-uniform)
  const int h = ((n0 & 1023) >> 6) + (wave >> 2);   // wave's head
  unsigned short* dst = (sel == 0) ? qout : ((sel == 1) ? kout : vout);
  // q pre-scaled by 1/sqrt(64) * log2(e) so attention softmax is pure exp2
  const float qsc = (sel == 0) ? 0.18033688f : 1.0f;
  __syncthreads();                         // s_ab dead; reuse as transpose tile
  unsigned short* tile = s_ab + wave * 2048;   // 32x64 u16 per wave (4 KB)
  if (sel < 2) {                           // q/k: RoPE in-register
#pragma unroll
    for (int i = 0; i < 2; ++i)
#pragma unroll
      for (int r = 0; r < 4; ++r) {
        const int row_l = i * 16 + quad * 4 + r;          // 0..31
        const int t = (m0 + wm + row_l) & 2047;
#pragma unroll
        for (int jg = 0; jg < 2; ++jg) {
          const int d = jg * 16 + m16;     // head-local 0..31
          const float c = ldsc(cosp, t * 32 + d, f32flag);
          const float sn = ldsc(sinp, t * 32 + d, f32flag);
          const float v1 = acc[i][jg][r];
          const float v2 = acc[i][jg + 2][r];
          tile[row_l * 64 + d]      = f2b((v1 * c - v2 * sn) * qsc);
          tile[row_l * 64 + d + 32] = f2b((v1 * sn + v2 * c) * qsc);
        }
      }
  } else {
#pragma unroll
    for (int i = 0; i < 2; ++i)
#pragma unroll
      for (int r = 0; r < 4; ++r) {
        const int row_l = i * 16 + quad * 4 + r;
#pragma unroll
        for (int j = 0; j < 4; ++j)
          tile[row_l * 64 + j * 16 + m16] = f2b(acc[i][j][r]);
      }
  }
  // wave-private read-back: 4 coalesced uint4 stores per lane
#pragma unroll
  for (int s = 0; s < 4; ++s) {
    const int row_l = s * 8 + (lane >> 3);
    const int seg = lane & 7;
    const int mrow_ = m0 + wm + row_l;
    const int bb = mrow_ >> 11;
    const int t = mrow_ & 2047;
    unsigned short* drow = dst + (((size_t)(bb * NH + h)) * TSZ + t) * HD;
    *(uint4*)(drow + seg * 8) = *(const uint4*)&tile[row_l * 64 + seg * 8];
  }
}

// ---------------------------------------------------------------------------
// MFMA bf16 GEMM (async staging):  C[M,N] = A[M,K] @ W[N,K]^T, bf16 operands.
// M-tile 128, N-tile 64, BK=64, K=1024. 256 threads; wave w owns rows
// wm=w*32 (2 i-tiles) x all 64 cols (4 j-tiles) -> acc[2][4] (32 AGPR).
// Used for the out-projection only (512 blocks -> 2/CU).
// ---------------------------------------------------------------------------
template <int EPI>
__global__ __launch_bounds__(256)
void gemm_bt_async(const void* __restrict__ Aorig, const unsigned short* __restrict__ Aconv,
                   const void* __restrict__ Worig, const unsigned short* __restrict__ Wconv,
                   void* __restrict__ C,
                   const int* __restrict__ dflag, int Nsz) {
  const int f32flag = *dflag;
  const unsigned short* A = f32flag ? Aconv : (const unsigned short*)Aorig;
  const unsigned short* W = f32flag ? Wconv : (const unsigned short*)Worig;

  const int tid = threadIdx.x;
  const int m0 = blockIdx.y * 128;
  const int n0 = blockIdx.x * 64;

  __shared__ __align__(16) unsigned short s_ab[128 * 64 + 64 * 64];  // 24 KB
  unsigned short* s_a = s_ab;
  unsigned short* s_b = s_ab + 128 * 64;

  const int lane = tid & 63;
  const int wave = tid >> 6;
  const int wm = wave * 32;                // wave's M offset (32 rows)
  const int m16 = lane & 15;
  const int quad = lane >> 4;

  const int srow = lane >> 3;
  const int schunk = (lane & 7) ^ srow;

  f32x4 acc[2][4];
#pragma unroll
  for (int i = 0; i < 2; ++i)
#pragma unroll
    for (int j = 0; j < 4; ++j) acc[i][j] = (f32x4){0.f, 0.f, 0.f, 0.f};

  for (int kt = 0; kt < DIMC; kt += 64) {
    __syncthreads();
#pragma unroll
    for (int u = 0; u < 4; ++u) {          // A: 128 rows
      const int r0 = u * 32 + wave * 8;
      async_cp16(A + (size_t)(m0 + r0 + srow) * DIMC + kt + schunk * 8, &s_a[r0 * 64]);
    }
#pragma unroll
    for (int u = 0; u < 2; ++u) {          // B: 64 rows
      const int r0 = u * 32 + wave * 8;
      async_cp16(W + (size_t)(n0 + r0 + srow) * DIMC + kt + schunk * 8, &s_b[r0 * 64]);
    }
    __syncthreads();
#pragma unroll
    for (int kk = 0; kk < 64; kk += 32) {
      const int cx = ((kk >> 3) + quad) ^ (m16 & 7);
      s16x8 af[2], bf[4];
#pragma unroll
      for (int i = 0; i < 2; ++i)
        af[i] = *(const s16x8*)&s_a[(wm + i * 16 + m16) * 64 + cx * 8];
#pragma unroll
      for (int j = 0; j < 4; ++j)
        bf[j] = *(const s16x8*)&s_b[(j * 16 + m16) * 64 + cx * 8];
#pragma unroll
      for (int i = 0; i < 2; ++i)
#pragma unroll
        for (int j = 0; j < 4; ++j)
          acc[i][j] = __builtin_amdgcn_mfma_f32_16x16x32_bf16(af[i], bf[j], acc[i][j], 0, 0, 0);
    }
  }

  // Epilogue. C/D layout: col = lane&15 (tile j), row = quad*4 + reg.
  if (f32flag) {
    float* Cf = (float*)C;
#pragma unroll
    for (int i = 0; i < 2; ++i)
#pragma unroll
      for (int j = 0; j < 4; ++j)
#pragma unroll
        for (int r = 0; r < 4; ++r) {
          const int mrow_ = m0 + wm + i * 16 + quad * 4 + r;
          const int col = n0 + j * 16 + m16;
          Cf[(size_t)mrow_ * Nsz + col] = acc[i][j][r];
        }
  } else {
    unsigned short* Ch = (unsigned short*)C;
#pragma unroll
    for (int i = 0; i < 2; ++i)
#pragma unroll
      for (int j = 0; j < 4; ++j)
#pragma unroll
        for (int r = 0; r < 4; ++r) {
          const int mrow_ = m0 + wm + i * 16 + quad * 4 + r;
          const int col = n0 + j * 16 + m16;
          Ch[(size_t)mrow_ * Nsz + col] = f2b(acc[i][j][r]);
        }
  }
}

// ---------------------------------------------------------------------------
// MFMA flash attention, S^T form, 512 threads (8 waves).
// Front/back subtile fusion: each block owns TWO 64-row q-subtiles of one
// (b,h) — waves 0-3 handle front subtile p, waves 4-7 the mirrored back
// subtile 31-p. Both consume the SAME KV chunk stream; every block does
// exactly 132 active wave-chunks. Co-resident pairs (c, c+256): duration
// sum 49, constant. Softmax in log2 domain (q pre-scaled by log2e),
// defer-max (THR=8), v_cvt_pk_bf16_f32 packing, setprio around MFMA
// clusters. Double-buffered K/V LDS: one barrier per chunk.
// ---------------------------------------------------------------------------
__device__ __forceinline__ void attn_pass(
    const unsigned short* __restrict__ qgh, const unsigned short* __restrict__ kgh,
    const unsigned short* __restrict__ vgh, unsigned short* __restrict__ outg,
    int b, int h, int qs, int nc, unsigned short* s_k0, unsigned short* s_k1,
    unsigned short* s_v0, unsigned short* s_v1, unsigned short* s_p,
    int tid, int lane, int w, int m16, int quad) {
  const unsigned short* qrow = qgh + (size_t)(qs + m16) * HD;
  const s16x8 bq0 = *(const s16x8*)(qrow + quad * 8);
  const s16x8 bq1 = *(const s16x8*)(qrow + 32 + quad * 8);

  f32x4 oacc[4];
#pragma unroll
  for (int dt = 0; dt < 4; ++dt) oacc[dt] = (f32x4){0.f, 0.f, 0.f, 0.f};
  float m_ = -1e30f, l_ = 0.f;

  const int krow = tid >> 3, kseg = tid & 7;   // 64 rows x 8 segs
  const int vkey = tid & 63, vseg = tid >> 6;  // 64 keys x 8 dsegs

  {  // prologue: chunk 0 into buf0
    const uint4 pk = *(const uint4*)(kgh + (size_t)krow * HD + kseg * 8);
    const uint4 pv = *(const uint4*)(vgh + (size_t)vkey * HD + vseg * 8);
    *(uint4*)&s_k0[krow * 72 + kseg * 8] = pk;
    const unsigned short* vv = (const unsigned short*)&pv;
#pragma unroll
    for (int jj = 0; jj < 8; ++jj) s_v0[(vseg * 8 + jj) * 72 + vkey] = vv[jj];
  }

  for (int kc = 0; kc < nc; ++kc) {
    unsigned short* sk = (kc & 1) ? s_k1 : s_k0;
    unsigned short* sv = (kc & 1) ? s_v1 : s_v0;
    unsigned short* skN = (kc & 1) ? s_k0 : s_k1;
    unsigned short* svN = (kc & 1) ? s_v0 : s_v1;
    __syncthreads();                       // buf[kc] ready; buf[kc+1] free
    uint4 pk, pv;
    const int pf = (kc + 1 < nc);
    if (pf) {                              // prefetch next chunk (overlaps compute)
      pk = *(const uint4*)(kgh + (size_t)((kc + 1) * 64 + krow) * HD + kseg * 8);
      pv = *(const uint4*)(vgh + (size_t)((kc + 1) * 64 + vkey) * HD + vseg * 8);
    }

    if (kc * 64 <= qs + 15) {              // not fully masked for this wave
      f32x4 sacc[4];
#pragma unroll
      for (int jt = 0; jt < 4; ++jt) sacc[jt] = (f32x4){0.f, 0.f, 0.f, 0.f};
      __builtin_amdgcn_s_setprio(1);
#pragma unroll
      for (int jt = 0; jt < 4; ++jt) {
        const s16x8 ak0 = *(const s16x8*)&sk[(jt * 16 + m16) * 72 + quad * 8];
        sacc[jt] = __builtin_amdgcn_mfma_f32_16x16x32_bf16(ak0, bq0, sacc[jt], 0, 0, 0);
        const s16x8 ak1 = *(const s16x8*)&sk[(jt * 16 + m16) * 72 + 32 + quad * 8];
        sacc[jt] = __builtin_amdgcn_mfma_f32_16x16x32_bf16(ak1, bq1, sacc[jt], 0, 0, 0);
      }
      __builtin_amdgcn_s_setprio(0);

      if (kc * 64 + 63 > qs) {             // diagonal region: element mask
#pragma unroll
        for (int jt = 0; jt < 4; ++jt)
#pragma unroll
          for (int r = 0; r < 4; ++r)
            if (kc * 64 + jt * 16 + quad * 4 + r > qs + m16) sacc[jt][r] = -1e30f;
      }

      // per-query tile max (scores are log2-scaled)
      float mx = sacc[0][0];
#pragma unroll
      for (int jt = 0; jt < 4; ++jt)
#pragma unroll
        for (int r = 0; r < 4; ++r) mx = fmaxf(mx, sacc[jt][r]);
      mx = fmaxf(mx, __shfl_xor(mx, 16, 64));
      mx = fmaxf(mx, __shfl_xor(mx, 32, 64));
      // defer-max: only rescale when the running max grew by > THR=8
      // (P bounded by 2^8=256; fp32 accumulation unaffected)
      if (!__all(mx <= m_ + 8.0f)) {
        const float mn = fmaxf(m_, mx);
        const float alpha = ex2(m_ - mn);
        m_ = mn;
        l_ *= alpha;
#pragma unroll
        for (int dt = 0; dt < 4; ++dt)
#pragma unroll
          for (int r = 0; r < 4; ++r) oacc[dt][r] *= alpha;
      }
      float rs = 0.f;
#pragma unroll
      for (int jt = 0; jt < 4; ++jt)
#pragma unroll
        for (int r = 0; r < 4; ++r) {
          const float p = ex2(sacc[jt][r] - m_);
          sacc[jt][r] = p;
          rs += p;
        }
      rs += __shfl_xor(rs, 16, 64);
      rs += __shfl_xor(rs, 32, 64);
      l_ += rs;

#pragma unroll
      for (int jt = 0; jt < 4; ++jt) {
        uint2 pw;
        pw.x = pk2(sacc[jt][0], sacc[jt][1]);
        pw.y = pk2(sacc[jt][2], sacc[jt][3]);
        *(uint2*)&s_p[(w * 16 + m16) * 72 + jt * 16 + quad * 4] = pw;
      }

      __builtin_amdgcn_s_setprio(1);
#pragma unroll
      for (int kk = 0; kk < 64; kk += 32) {
        const s16x8 bp = *(const s16x8*)&s_p[(w * 16 + m16) * 72 + kk + quad * 8];
#pragma unroll
        for (int dt = 0; dt < 4; ++dt) {
          const s16x8 av = *(const s16x8*)&sv[(dt * 16 + m16) * 72 + kk + quad * 8];
          oacc[dt] = __builtin_amdgcn_mfma_f32_16x16x32_bf16(av, bp, oacc[dt], 0, 0, 0);
        }
      }
      __builtin_amdgcn_s_setprio(0);
    }

    if (pf) {                              // store next chunk into other buffer
      *(uint4*)&skN[krow * 72 + kseg * 8] = pk;
      const unsigned short* vv = (const unsigned short*)&pv;
#pragma unroll
      for (int jj = 0; jj < 8; ++jj) svN[(vseg * 8 + jj) * 72 + vkey] = vv[jj];
    }
  }

  // epilogue: normalize, transpose via wave-private s_p rows, coalesced store
  const float linv = 1.0f / l_;
#pragma unroll
  for (int dt = 0; dt < 4; ++dt) {
    uint2 ow;
    ow.x = pk2(oacc[dt][0] * linv, oacc[dt][1] * linv);
    ow.y = pk2(oacc[dt][2] * linv, oacc[dt][3] * linv);
    *(uint2*)&s_p[(w * 16 + m16) * 72 + dt * 16 + quad * 4] = ow;
  }
  {
    const int qq = lane >> 2, dseg = lane & 3;   // wave-private rows: no barrier
    const uint4 o0 = *(const uint4*)&s_p[(w * 16 + qq) * 72 + dseg * 16];
    const uint4 o1 = *(const uint4*)&s_p[(w * 16 + qq) * 72 + dseg * 16 + 8];
    unsigned short* orow =
        outg + ((size_t)b * TSZ + qs + qq) * DIMC + h * 64 + dseg * 16;
    *(uint4*)orow = o0;
    *(uint4*)(orow + 8) = o1;
  }
}

__global__ __launch_bounds__(512)
void attn_fwd_mfma(const unsigned short* __restrict__ qg,
                   const unsigned short* __restrict__ kg,
                   const unsigned short* __restrict__ vg,
                   unsigned short* __restrict__ outg) {
  const int tid = threadIdx.x;
  const int lane = tid & 63;
  const int w = tid >> 6;                // wave 0..7
  const int m16 = lane & 15;
  const int quad = lane >> 4;
  const int l = (int)blockIdx.x;         // 0..511
  // Pair id p: l<256 -> p = g (nc=32-g, long, dispatched first);
  // l>=256 -> p = 15-g (nc=17+g, short). Co-resident pair (c, c+256):
  // durations (32-g)+(17+g) = 49, constant for every CU.
  const int g = (l & 255) >> 5;          // 0..7
  const int p = (l < 256) ? g : (15 - g);
  const int nc = 32 - p;                 // KV chunks for the back subtile
  const int bh = l & 31;
  const int b = bh >> 4, h = bh & 15;
  const size_t base = (size_t)bh * TSZ * HD;
  // waves 0-3: front subtile p; waves 4-7: back subtile 31-p
  const int sub = (w < 4) ? p : (31 - p);
  const int qs = sub * 64 + (w & 3) * 16;   // wave's first query row

  __shared__ __align__(16) unsigned short s_k0[64 * 72];
  __shared__ __align__(16) unsigned short s_k1[64 * 72];
  __shared__ __align__(16) unsigned short s_v0[64 * 72];
  __shared__ __align__(16) unsigned short s_v1[64 * 72];
  __shared__ __align__(16) unsigned short s_p[128 * 72];

  attn_pass(qg + base, kg + base, vg + base, outg, b, h, qs, nc,
            s_k0, s_k1, s_v0, s_v1, s_p, tid, lane, w, m16, quad);
}

// ---------------------------------------------------------------------------
extern "C" void kernel_launch(void* const* d_in, const int* in_sizes, int n_in,
                              void* d_out, int out_size, void* d_ws, size_t ws_size,
                              hipStream_t stream) {
  (void)in_sizes; (void)n_in; (void)out_size; (void)ws_size;
  const void* x    = d_in[0];
  const void* cosp = d_in[1];
  const void* sinp = d_in[2];
  const void* wqkv = d_in[3];
  const void* wout = d_in[4];

  int* dflag = (int*)d_ws;
  const size_t per = (size_t)BSZ * NH * TSZ * HD;       // 4,194,304 elems
  unsigned short* q = (unsigned short*)((char*)d_ws + 256);
  unsigned short* k = q + per;
  unsigned short* v = k + per;
  unsigned short* attnb = v + per;                      // [B,T,DIM] bf16
  unsigned short* xb   = attnb + (size_t)MROWS * DIMC;  // bf16 copies (fp32 case)
  unsigned short* wqb  = xb + (size_t)MROWS * DIMC;
  unsigned short* wob  = wqb + (size_t)3 * DIMC * DIMC;

  detect_dtype<<<1, 64, 0, stream>>>((const unsigned short*)cosp, dflag);
  cvt_all<<<dim3(4096), dim3(256), 0, stream>>>(
      (const float*)x, (const float*)wqkv, (const float*)wout, xb, wqb, wob, dflag);
  // QKV projection: 128x128 tiles, 512 threads -> 768 blocks, 2-3/CU resident
  gemm_qkv128<<<dim3(3 * DIMC / 128, MROWS / 128), dim3(512), 0, stream>>>(
      x, xb, wqkv, wqb, cosp, sinp, q, k, v, dflag);
  // causal flash attention: 512 front/back-fused blocks, balanced durations
  attn_fwd_mfma<<<dim3(512), dim3(512), 0, stream>>>(q, k, v, attnb);
  // out-projection: 128x64 tiles -> 512 blocks
  gemm_bt_async<0><<<dim3(DIMC / 64, MROWS / 128), dim3(256), 0, stream>>>(
      attnb, attnb, wout, wob, d_out, dflag, DIMC);
}

// Round 5
// 177.735 us; speedup vs baseline: 1.0875x; 1.0296x over previous
//
#include <hip/hip_runtime.h>

// ---------------- problem constants ----------------
#define DIMC 1024
#define NH   16
#define HD   64
#define BSZ  2
#define TSZ  2048
#define MROWS (BSZ*TSZ)   // 4096

typedef __attribute__((ext_vector_type(8))) short s16x8;   // 8 bf16 (4 VGPRs)
typedef __attribute__((ext_vector_type(4))) float f32x4;   // 4 fp32

__device__ __forceinline__ float b2f(unsigned short u) {
  return __uint_as_float(((unsigned)u) << 16);
}
__device__ __forceinline__ unsigned short f2b(float f) {
  unsigned x = __float_as_uint(f);
  unsigned r = x + 0x7fffu + ((x >> 16) & 1u);   // RTNE
  return (unsigned short)(r >> 16);
}
// single-instruction packed f32->bf16 (RTNE), lo = a, hi = b  [T12 recipe]
__device__ __forceinline__ unsigned pk2(float a, float b) {
  unsigned r;
  asm("v_cvt_pk_bf16_f32 %0, %1, %2" : "=v"(r) : "v"(a), "v"(b));
  return r;
}
// 2^x in one v_exp_f32 (softmax runs in log2 domain)
__device__ __forceinline__ float ex2(float x) {
#if __has_builtin(__builtin_amdgcn_exp2f)
  return __builtin_amdgcn_exp2f(x);
#else
  float r; asm("v_exp_f32 %0, %1" : "=v"(r) : "v"(x)); return r;
#endif
}
__device__ __forceinline__ float ldsc(const void* __restrict__ p, int idx, int isf32) {
  return isf32 ? ((const float*)p)[idx] : b2f(((const unsigned short*)p)[idx]);
}

// 16-byte global -> LDS DMA. lds base wave-uniform; HW writes lane i at base+16i.
__device__ __forceinline__ void async_cp16(const unsigned short* g, unsigned short* l) {
  __builtin_amdgcn_global_load_lds(
      (const __attribute__((address_space(1))) unsigned int*)g,
      (__attribute__((address_space(3))) unsigned int*)l, 16, 0, 0);
}

// ---------------------------------------------------------------------------
__global__ void detect_dtype(const unsigned short* __restrict__ cosp, int* __restrict__ flag) {
  const int i = threadIdx.x;   // 64 threads
  const unsigned long long m = __ballot(cosp[i] >= 0x4000u);
  if (i == 0) *flag = (m != 0ull) ? 1 : 0;
}

// ---------------------------------------------------------------------------
// One-shot fp32 -> bf16 conversion of x, w_qkv, w_out (only when inputs fp32).
// ---------------------------------------------------------------------------
__global__ __launch_bounds__(256)
void cvt_all(const float* __restrict__ x, const float* __restrict__ wq,
             const float* __restrict__ wo,
             unsigned short* __restrict__ xb, unsigned short* __restrict__ wqb,
             unsigned short* __restrict__ wob, const int* __restrict__ flag) {
  if (*flag == 0) return;
  const unsigned id = blockIdx.x * 256 + threadIdx.x;  // 0..1048575
  const float* src; unsigned short* dst; unsigned off;
  if (id < 524288u) { src = x; dst = xb; off = id; }
  else if (id < 917504u) { src = wq; dst = wqb; off = id - 524288u; }
  else { src = wo; dst = wob; off = id - 917504u; }
  const float4 a = ((const float4*)src)[off * 2];
  const float4 b = ((const float4*)src)[off * 2 + 1];
  uint4 u;
  u.x = pk2(a.x, a.y); u.y = pk2(a.z, a.w);
  u.z = pk2(b.x, b.y); u.w = pk2(b.z, b.w);
  ((uint4*)dst)[off] = u;
}

// ---------------------------------------------------------------------------
// QKV projection GEMM, 128x128 tile, 512 threads / 8 waves (4M x 2N wave
// grid), BK=64, K=1024. 2-PHASE PIPELINE (T3 minimum): LDS double-buffered
// (2 x 32 KB); STAGE(t+1) is issued BEFORE compute(t), so the __syncthreads
// vmcnt(0) drain at the end of the iteration waits for loads that flew
// during the ~350-cycle MFMA phase (round-4 structure waited immediately
// after issue -> full latency exposed every K-step, both pipes <20% busy).
// Per-wave 32x64 -> acc[2][4] (32 regs), VGPR ~60 -> residency not
// register-bound. Grid (24, 32) = 768 blocks. Epilogue: RoPE (q pre-scaled
// by 0.125*log2e), per-wave 32x64 LDS transpose tile, coalesced uint4
// scatter into q/k/v [B,H,T,64] bf16.
// ---------------------------------------------------------------------------
__global__ __launch_bounds__(512, 4)
void gemm_qkv128(const void* __restrict__ Aorig, const unsigned short* __restrict__ Aconv,
                 const void* __restrict__ Worig, const unsigned short* __restrict__ Wconv,
                 const void* __restrict__ cosp, const void* __restrict__ sinp,
                 unsigned short* __restrict__ qout,
                 unsigned short* __restrict__ kout,
                 unsigned short* __restrict__ vout,
                 const int* __restrict__ dflag) {
  const int f32flag = *dflag;
  const unsigned short* A = f32flag ? Aconv : (const unsigned short*)Aorig;
  const unsigned short* W = f32flag ? Wconv : (const unsigned short*)Worig;

  const int tid = threadIdx.x;
  const int m0 = blockIdx.y * 128;
  const int n0 = blockIdx.x * 128;

  // [buf][A(128x64) | B(128x64)] u16 -> 2 x 32 KB = 64 KB
  __shared__ __align__(16) unsigned short s_ab[2 * 16384];

  const int lane = tid & 63;
  const int wave = tid >> 6;               // 0..7
  const int wm = (wave & 3) * 32;          // wave's M offset (32 rows)
  const int wn = (wave >> 2) * 64;         // wave's N offset (64 cols = 1 head)
  const int m16 = lane & 15;
  const int quad = lane >> 4;

  const int srow = lane >> 3;
  const int schunk = (lane & 7) ^ srow;    // XOR pre-swizzle of source chunks

  const unsigned short* ga = A + (size_t)(m0 + wave * 8 + srow) * DIMC + schunk * 8;
  const unsigned short* gb = W + (size_t)(n0 + wave * 8 + srow) * DIMC + schunk * 8;

  f32x4 acc[2][4];
#pragma unroll
  for (int i = 0; i < 2; ++i)
#pragma unroll
    for (int j = 0; j < 4; ++j) acc[i][j] = (f32x4){0.f, 0.f, 0.f, 0.f};

  auto stage = [&](int b, int kt) {
    unsigned short* sa = s_ab + b * 16384;
#pragma unroll
    for (int u = 0; u < 2; ++u) {          // A and B: 128 rows each, 8 waves
      async_cp16(ga + (size_t)(u * 64) * DIMC + kt, &sa[(u * 64 + wave * 8) * 64]);
      async_cp16(gb + (size_t)(u * 64) * DIMC + kt, &sa[8192 + (u * 64 + wave * 8) * 64]);
    }
  };

  stage(0, 0);
  __syncthreads();                         // tile 0 landed

  for (int t = 0; t < 16; ++t) {
    const int cur = t & 1;
    if (t < 15) stage(cur ^ 1, (t + 1) * 64);   // issue-early: flies during MFMA
    const unsigned short* sa = s_ab + cur * 16384;
    const unsigned short* sb = sa + 8192;
    __builtin_amdgcn_s_setprio(1);
#pragma unroll
    for (int kk = 0; kk < 64; kk += 32) {
      const int cx = ((kk >> 3) + quad) ^ (m16 & 7);
      s16x8 af[2], bf[4];
#pragma unroll
      for (int i = 0; i < 2; ++i)
        af[i] = *(const s16x8*)&sa[(wm + i * 16 + m16) * 64 + cx * 8];
#pragma unroll
      for (int j = 0; j < 4; ++j)
        bf[j] = *(const s16x8*)&sb[(wn + j * 16 + m16) * 64 + cx * 8];
#pragma unroll
      for (int i = 0; i < 2; ++i)
#pragma unroll
        for (int j = 0; j < 4; ++j)
          acc[i][j] = __builtin_amdgcn_mfma_f32_16x16x32_bf16(af[i], bf[j], acc[i][j], 0, 0, 0);
    }
    __builtin_amdgcn_s_setprio(0);
    __syncthreads();                       // wait-late: drains tile t+1 loads
  }

  // Epilogue. C/D layout: col = lane&15 (within tile j), row = quad*4 + reg.
  const int sel = n0 >> 10;                // 0=q 1=k 2=v (block-uniform)
  const int h = ((n0 & 1023) >> 6) + (wave >> 2);   // wave's head
  unsigned short* dst = (sel == 0) ? qout : ((sel == 1) ? kout : vout);
  // q pre-scaled by 1/sqrt(64) * log2(e) so attention softmax is pure exp2
  const float qsc = (sel == 0) ? 0.18033688f : 1.0f;
  unsigned short* tile = s_ab + wave * 2048;   // 32x64 u16 per wave (4 KB)
  if (sel < 2) {                           // q/k: RoPE in-register
#pragma unroll
    for (int i = 0; i < 2; ++i)
#pragma unroll
      for (int r = 0; r < 4; ++r) {
        const int row_l = i * 16 + quad * 4 + r;          // 0..31
        const int t = (m0 + wm + row_l) & 2047;
#pragma unroll
        for (int jg = 0; jg < 2; ++jg) {
          const int d = jg * 16 + m16;     // head-local 0..31
          const float c = ldsc(cosp, t * 32 + d, f32flag);
          const float sn = ldsc(sinp, t * 32 + d, f32flag);
          const float v1 = acc[i][jg][r];
          const float v2 = acc[i][jg + 2][r];
          tile[row_l * 64 + d]      = f2b((v1 * c - v2 * sn) * qsc);
          tile[row_l * 64 + d + 32] = f2b((v1 * sn + v2 * c) * qsc);
        }
      }
  } else {
#pragma unroll
    for (int i = 0; i < 2; ++i)
#pragma unroll
      for (int r = 0; r < 4; ++r) {
        const int row_l = i * 16 + quad * 4 + r;
#pragma unroll
        for (int j = 0; j < 4; ++j)
          tile[row_l * 64 + j * 16 + m16] = f2b(acc[i][j][r]);
      }
  }
  // wave-private read-back: 4 coalesced uint4 stores per lane
#pragma unroll
  for (int s = 0; s < 4; ++s) {
    const int row_l = s * 8 + (lane >> 3);
    const int seg = lane & 7;
    const int mrow_ = m0 + wm + row_l;
    const int bb = mrow_ >> 11;
    const int t = mrow_ & 2047;
    unsigned short* drow = dst + (((size_t)(bb * NH + h)) * TSZ + t) * HD;
    *(uint4*)(drow + seg * 8) = *(const uint4*)&tile[row_l * 64 + seg * 8];
  }
}

// ---------------------------------------------------------------------------
// Out-projection GEMM: C[M,1024] = A[M,K] @ W[1024,K]^T. M-tile 128, N-tile
// 64, BK=64, 256 threads / 4 waves; wave owns 32x64 -> acc[2][4]. Same
// 2-phase issue-early/wait-late pipeline (LDS 2 x 24 KB = 48 KB -> 3
// blocks/CU by LDS, grid 512 = 2/CU). fp32 epilogue: per-wave 32x68-stride
// LDS transpose then 8 coalesced float4 stores per lane (round-4 version
// did 32 scalar dword stores per lane).
// ---------------------------------------------------------------------------
__global__ __launch_bounds__(256)
void gemm_out(const void* __restrict__ Aorig, const unsigned short* __restrict__ Aconv,
              const void* __restrict__ Worig, const unsigned short* __restrict__ Wconv,
              void* __restrict__ C, const int* __restrict__ dflag, int Nsz) {
  const int f32flag = *dflag;
  const unsigned short* A = f32flag ? Aconv : (const unsigned short*)Aorig;
  const unsigned short* W = f32flag ? Wconv : (const unsigned short*)Worig;

  const int tid = threadIdx.x;
  const int m0 = blockIdx.y * 128;
  const int n0 = blockIdx.x * 64;

  // [buf][A(128x64) | B(64x64)] u16 -> 2 x 24 KB = 48 KB
  __shared__ __align__(16) unsigned short s_ab[2 * 12288];

  const int lane = tid & 63;
  const int wave = tid >> 6;               // 0..3
  const int wm = wave * 32;
  const int m16 = lane & 15;
  const int quad = lane >> 4;

  const int srow = lane >> 3;
  const int schunk = (lane & 7) ^ srow;

  const unsigned short* ga = A + (size_t)(m0 + wave * 8 + srow) * DIMC + schunk * 8;
  const unsigned short* gb = W + (size_t)(n0 + wave * 8 + srow) * DIMC + schunk * 8;

  f32x4 acc[2][4];
#pragma unroll
  for (int i = 0; i < 2; ++i)
#pragma unroll
    for (int j = 0; j < 4; ++j) acc[i][j] = (f32x4){0.f, 0.f, 0.f, 0.f};

  auto stage = [&](int b, int kt) {
    unsigned short* sa = s_ab + b * 12288;
#pragma unroll
    for (int u = 0; u < 4; ++u)            // A: 128 rows, 4 waves x 8 rows
      async_cp16(ga + (size_t)(u * 32) * DIMC + kt, &sa[(u * 32 + wave * 8) * 64]);
#pragma unroll
    for (int u = 0; u < 2; ++u)            // B: 64 rows
      async_cp16(gb + (size_t)(u * 32) * DIMC + kt, &sa[8192 + (u * 32 + wave * 8) * 64]);
  };

  stage(0, 0);
  __syncthreads();

  for (int t = 0; t < 16; ++t) {
    const int cur = t & 1;
    if (t < 15) stage(cur ^ 1, (t + 1) * 64);
    const unsigned short* sa = s_ab + cur * 12288;
    const unsigned short* sb = sa + 8192;
    __builtin_amdgcn_s_setprio(1);
#pragma unroll
    for (int kk = 0; kk < 64; kk += 32) {
      const int cx = ((kk >> 3) + quad) ^ (m16 & 7);
      s16x8 af[2], bf[4];
#pragma unroll
      for (int i = 0; i < 2; ++i)
        af[i] = *(const s16x8*)&sa[(wm + i * 16 + m16) * 64 + cx * 8];
#pragma unroll
      for (int j = 0; j < 4; ++j)
        bf[j] = *(const s16x8*)&sb[(j * 16 + m16) * 64 + cx * 8];
#pragma unroll
      for (int i = 0; i < 2; ++i)
#pragma unroll
        for (int j = 0; j < 4; ++j)
          acc[i][j] = __builtin_amdgcn_mfma_f32_16x16x32_bf16(af[i], bf[j], acc[i][j], 0, 0, 0);
    }
    __builtin_amdgcn_s_setprio(0);
    __syncthreads();
  }

  // Epilogue. C/D layout: col = lane&15 (tile j), row = quad*4 + reg.
  if (f32flag) {
    // per-wave 32x64 f32 transpose tile, stride 68 floats (bank-clean,
    // 16B-aligned rows): 4 waves x 8704 B = 34 KB inside the 48 KB s_ab.
    float* ftile = (float*)s_ab + wave * (32 * 68);
#pragma unroll
    for (int i = 0; i < 2; ++i)
#pragma unroll
      for (int j = 0; j < 4; ++j)
#pragma unroll
        for (int r = 0; r < 4; ++r)
          ftile[(i * 16 + quad * 4 + r) * 68 + j * 16 + m16] = acc[i][j][r];
    float* Cf = (float*)C;
#pragma unroll
    for (int i = 0; i < 2; ++i)
#pragma unroll
      for (int s = 0; s < 4; ++s) {
        const int row_l = i * 16 + s * 4 + (lane >> 4);
        const float4 vv = *(const float4*)&ftile[row_l * 68 + (lane & 15) * 4];
        *(float4*)&Cf[(size_t)(m0 + wm + row_l) * Nsz + n0 + (lane & 15) * 4] = vv;
      }
  } else {
    unsigned short* Ch = (unsigned short*)C;
#pragma unroll
    for (int i = 0; i < 2; ++i)
#pragma unroll
      for (int j = 0; j < 4; ++j)
#pragma unroll
        for (int r = 0; r < 4; ++r) {
          const int mrow_ = m0 + wm + i * 16 + quad * 4 + r;
          const int col = n0 + j * 16 + m16;
          Ch[(size_t)mrow_ * Nsz + col] = f2b(acc[i][j][r]);
        }
  }
}

// ---------------------------------------------------------------------------
// MFMA flash attention, S^T form, 512 threads (8 waves).
// Front/back subtile fusion: each block owns TWO 64-row q-subtiles of one
// (b,h) — waves 0-3 handle front subtile p, waves 4-7 the mirrored back
// subtile 31-p. Both consume the SAME KV chunk stream; every block does
// exactly 132 active wave-chunks. Co-resident pairs (c, c+256): duration
// sum 49, constant. Softmax in log2 domain (q pre-scaled by log2e),
// defer-max (THR=8), v_cvt_pk_bf16_f32 packing, setprio around MFMA
// clusters. Double-buffered K/V LDS: one barrier per chunk.
// ---------------------------------------------------------------------------
__device__ __forceinline__ void attn_pass(
    const unsigned short* __restrict__ qgh, const unsigned short* __restrict__ kgh,
    const unsigned short* __restrict__ vgh, unsigned short* __restrict__ outg,
    int b, int h, int qs, int nc, unsigned short* s_k0, unsigned short* s_k1,
    unsigned short* s_v0, unsigned short* s_v1, unsigned short* s_p,
    int tid, int lane, int w, int m16, int quad) {
  const unsigned short* qrow = qgh + (size_t)(qs + m16) * HD;
  const s16x8 bq0 = *(const s16x8*)(qrow + quad * 8);
  const s16x8 bq1 = *(const s16x8*)(qrow + 32 + quad * 8);

  f32x4 oacc[4];
#pragma unroll
  for (int dt = 0; dt < 4; ++dt) oacc[dt] = (f32x4){0.f, 0.f, 0.f, 0.f};
  float m_ = -1e30f, l_ = 0.f;

  const int krow = tid >> 3, kseg = tid & 7;   // 64 rows x 8 segs
  const int vkey = tid & 63, vseg = tid >> 6;  // 64 keys x 8 dsegs

  {  // prologue: chunk 0 into buf0
    const uint4 pk = *(const uint4*)(kgh + (size_t)krow * HD + kseg * 8);
    const uint4 pv = *(const uint4*)(vgh + (size_t)vkey * HD + vseg * 8);
    *(uint4*)&s_k0[krow * 72 + kseg * 8] = pk;
    const unsigned short* vv = (const unsigned short*)&pv;
#pragma unroll
    for (int jj = 0; jj < 8; ++jj) s_v0[(vseg * 8 + jj) * 72 + vkey] = vv[jj];
  }

  for (int kc = 0; kc < nc; ++kc) {
    unsigned short* sk = (kc & 1) ? s_k1 : s_k0;
    unsigned short* sv = (kc & 1) ? s_v1 : s_v0;
    unsigned short* skN = (kc & 1) ? s_k0 : s_k1;
    unsigned short* svN = (kc & 1) ? s_v0 : s_v1;
    __syncthreads();                       // buf[kc] ready; buf[kc+1] free
    uint4 pk, pv;
    const int pf = (kc + 1 < nc);
    if (pf) {                              // prefetch next chunk (overlaps compute)
      pk = *(const uint4*)(kgh + (size_t)((kc + 1) * 64 + krow) * HD + kseg * 8);
      pv = *(const uint4*)(vgh + (size_t)((kc + 1) * 64 + vkey) * HD + vseg * 8);
    }

    if (kc * 64 <= qs + 15) {              // not fully masked for this wave
      f32x4 sacc[4];
#pragma unroll
      for (int jt = 0; jt < 4; ++jt) sacc[jt] = (f32x4){0.f, 0.f, 0.f, 0.f};
      __builtin_amdgcn_s_setprio(1);
#pragma unroll
      for (int jt = 0; jt < 4; ++jt) {
        const s16x8 ak0 = *(const s16x8*)&sk[(jt * 16 + m16) * 72 + quad * 8];
        sacc[jt] = __builtin_amdgcn_mfma_f32_16x16x32_bf16(ak0, bq0, sacc[jt], 0, 0, 0);
        const s16x8 ak1 = *(const s16x8*)&sk[(jt * 16 + m16) * 72 + 32 + quad * 8];
        sacc[jt] = __builtin_amdgcn_mfma_f32_16x16x32_bf16(ak1, bq1, sacc[jt], 0, 0, 0);
      }
      __builtin_amdgcn_s_setprio(0);

      if (kc * 64 + 63 > qs) {             // diagonal region: element mask
#pragma unroll
        for (int jt = 0; jt < 4; ++jt)
#pragma unroll
          for (int r = 0; r < 4; ++r)
            if (kc * 64 + jt * 16 + quad * 4 + r > qs + m16) sacc[jt][r] = -1e30f;
      }

      // per-query tile max (scores are log2-scaled)
      float mx = sacc[0][0];
#pragma unroll
      for (int jt = 0; jt < 4; ++jt)
#pragma unroll
        for (int r = 0; r < 4; ++r) mx = fmaxf(mx, sacc[jt][r]);
      mx = fmaxf(mx, __shfl_xor(mx, 16, 64));
      mx = fmaxf(mx, __shfl_xor(mx, 32, 64));
      // defer-max: only rescale when the running max grew by > THR=8
      // (P bounded by 2^8=256; fp32 accumulation unaffected)
      if (!__all(mx <= m_ + 8.0f)) {
        const float mn = fmaxf(m_, mx);
        const float alpha = ex2(m_ - mn);
        m_ = mn;
        l_ *= alpha;
#pragma unroll
        for (int dt = 0; dt < 4; ++dt)
#pragma unroll
          for (int r = 0; r < 4; ++r) oacc[dt][r] *= alpha;
      }
      float rs = 0.f;
#pragma unroll
      for (int jt = 0; jt < 4; ++jt)
#pragma unroll
        for (int r = 0; r < 4; ++r) {
          const float p = ex2(sacc[jt][r] - m_);
          sacc[jt][r] = p;
          rs += p;
        }
      rs += __shfl_xor(rs, 16, 64);
      rs += __shfl_xor(rs, 32, 64);
      l_ += rs;

#pragma unroll
      for (int jt = 0; jt < 4; ++jt) {
        uint2 pw;
        pw.x = pk2(sacc[jt][0], sacc[jt][1]);
        pw.y = pk2(sacc[jt][2], sacc[jt][3]);
        *(uint2*)&s_p[(w * 16 + m16) * 72 + jt * 16 + quad * 4] = pw;
      }

      __builtin_amdgcn_s_setprio(1);
#pragma unroll
      for (int kk = 0; kk < 64; kk += 32) {
        const s16x8 bp = *(const s16x8*)&s_p[(w * 16 + m16) * 72 + kk + quad * 8];
#pragma unroll
        for (int dt = 0; dt < 4; ++dt) {
          const s16x8 av = *(const s16x8*)&sv[(dt * 16 + m16) * 72 + kk + quad * 8];
          oacc[dt] = __builtin_amdgcn_mfma_f32_16x16x32_bf16(av, bp, oacc[dt], 0, 0, 0);
        }
      }
      __builtin_amdgcn_s_setprio(0);
    }

    if (pf) {                              // store next chunk into other buffer
      *(uint4*)&skN[krow * 72 + kseg * 8] = pk;
      const unsigned short* vv = (const unsigned short*)&pv;
#pragma unroll
      for (int jj = 0; jj < 8; ++jj) svN[(vseg * 8 + jj) * 72 + vkey] = vv[jj];
    }
  }

  // epilogue: normalize, transpose via wave-private s_p rows, coalesced store
  const float linv = 1.0f / l_;
#pragma unroll
  for (int dt = 0; dt < 4; ++dt) {
    uint2 ow;
    ow.x = pk2(oacc[dt][0] * linv, oacc[dt][1] * linv);
    ow.y = pk2(oacc[dt][2] * linv, oacc[dt][3] * linv);
    *(uint2*)&s_p[(w * 16 + m16) * 72 + dt * 16 + quad * 4] = ow;
  }
  {
    const int qq = lane >> 2, dseg = lane & 3;   // wave-private rows: no barrier
    const uint4 o0 = *(const uint4*)&s_p[(w * 16 + qq) * 72 + dseg * 16];
    const uint4 o1 = *(const uint4*)&s_p[(w * 16 + qq) * 72 + dseg * 16 + 8];
    unsigned short* orow =
        outg + ((size_t)b * TSZ + qs + qq) * DIMC + h * 64 + dseg * 16;
    *(uint4*)orow = o0;
    *(uint4*)(orow + 8) = o1;
  }
}

__global__ __launch_bounds__(512)
void attn_fwd_mfma(const unsigned short* __restrict__ qg,
                   const unsigned short* __restrict__ kg,
                   const unsigned short* __restrict__ vg,
                   unsigned short* __restrict__ outg) {
  const int tid = threadIdx.x;
  const int lane = tid & 63;
  const int w = tid >> 6;                // wave 0..7
  const int m16 = lane & 15;
  const int quad = lane >> 4;
  const int l = (int)blockIdx.x;         // 0..511
  // Pair id p: l<256 -> p = g (nc=32-g, long, dispatched first);
  // l>=256 -> p = 15-g (nc=17+g, short). Co-resident pair (c, c+256):
  // durations (32-g)+(17+g) = 49, constant for every CU.
  const int g = (l & 255) >> 5;          // 0..7
  const int p = (l < 256) ? g : (15 - g);
  const int nc = 32 - p;                 // KV chunks for the back subtile
  const int bh = l & 31;
  const int b = bh >> 4, h = bh & 15;
  const size_t base = (size_t)bh * TSZ * HD;
  // waves 0-3: front subtile p; waves 4-7: back subtile 31-p
  const int sub = (w < 4) ? p : (31 - p);
  const int qs = sub * 64 + (w & 3) * 16;   // wave's first query row

  __shared__ __align__(16) unsigned short s_k0[64 * 72];
  __shared__ __align__(16) unsigned short s_k1[64 * 72];
  __shared__ __align__(16) unsigned short s_v0[64 * 72];
  __shared__ __align__(16) unsigned short s_v1[64 * 72];
  __shared__ __align__(16) unsigned short s_p[128 * 72];

  attn_pass(qg + base, kg + base, vg + base, outg, b, h, qs, nc,
            s_k0, s_k1, s_v0, s_v1, s_p, tid, lane, w, m16, quad);
}

// ---------------------------------------------------------------------------
extern "C" void kernel_launch(void* const* d_in, const int* in_sizes, int n_in,
                              void* d_out, int out_size, void* d_ws, size_t ws_size,
                              hipStream_t stream) {
  (void)in_sizes; (void)n_in; (void)out_size; (void)ws_size;
  const void* x    = d_in[0];
  const void* cosp = d_in[1];
  const void* sinp = d_in[2];
  const void* wqkv = d_in[3];
  const void* wout = d_in[4];

  int* dflag = (int*)d_ws;
  const size_t per = (size_t)BSZ * NH * TSZ * HD;       // 4,194,304 elems
  unsigned short* q = (unsigned short*)((char*)d_ws + 256);
  unsigned short* k = q + per;
  unsigned short* v = k + per;
  unsigned short* attnb = v + per;                      // [B,T,DIM] bf16
  unsigned short* xb   = attnb + (size_t)MROWS * DIMC;  // bf16 copies (fp32 case)
  unsigned short* wqb  = xb + (size_t)MROWS * DIMC;
  unsigned short* wob  = wqb + (size_t)3 * DIMC * DIMC;

  detect_dtype<<<1, 64, 0, stream>>>((const unsigned short*)cosp, dflag);
  cvt_all<<<dim3(4096), dim3(256), 0, stream>>>(
      (const float*)x, (const float*)wqkv, (const float*)wout, xb, wqb, wob, dflag);
  // QKV projection: 128x128 tiles, 512 threads, 2-phase pipeline
  gemm_qkv128<<<dim3(3 * DIMC / 128, MROWS / 128), dim3(512), 0, stream>>>(
      x, xb, wqkv, wqb, cosp, sinp, q, k, v, dflag);
  // causal flash attention: 512 front/back-fused blocks, balanced durations
  attn_fwd_mfma<<<dim3(512), dim3(512), 0, stream>>>(q, k, v, attnb);
  // out-projection: 128x64 tiles, 2-phase pipeline + coalesced f32 epilogue
  gemm_out<<<dim3(DIMC / 64, MROWS / 128), dim3(256), 0, stream>>>(
      attnb, attnb, wout, wob, d_out, dflag, DIMC);
}

// Round 6
// 174.607 us; speedup vs baseline: 1.1070x; 1.0179x over previous
//
#include <hip/hip_runtime.h>

// ---------------- problem constants ----------------
#define DIMC 1024
#define NH   16
#define HD   64
#define BSZ  2
#define TSZ  2048
#define MROWS (BSZ*TSZ)   // 4096

typedef __attribute__((ext_vector_type(8))) short s16x8;   // 8 bf16 (4 VGPRs)
typedef __attribute__((ext_vector_type(4))) float f32x4;   // 4 fp32

__device__ __forceinline__ float b2f(unsigned short u) {
  return __uint_as_float(((unsigned)u) << 16);
}
__device__ __forceinline__ unsigned short f2b(float f) {
  unsigned x = __float_as_uint(f);
  unsigned r = x + 0x7fffu + ((x >> 16) & 1u);   // RTNE
  return (unsigned short)(r >> 16);
}
// single-instruction packed f32->bf16 (RTNE), lo = a, hi = b  [T12 recipe]
__device__ __forceinline__ unsigned pk2(float a, float b) {
  unsigned r;
  asm("v_cvt_pk_bf16_f32 %0, %1, %2" : "=v"(r) : "v"(a), "v"(b));
  return r;
}
// 2^x in one v_exp_f32 (softmax runs in log2 domain)
__device__ __forceinline__ float ex2(float x) {
#if __has_builtin(__builtin_amdgcn_exp2f)
  return __builtin_amdgcn_exp2f(x);
#else
  float r; asm("v_exp_f32 %0, %1" : "=v"(r) : "v"(x)); return r;
#endif
}
__device__ __forceinline__ float ldsc(const void* __restrict__ p, int idx, int isf32) {
  return isf32 ? ((const float*)p)[idx] : b2f(((const unsigned short*)p)[idx]);
}

// 16-byte global -> LDS DMA. lds base wave-uniform; HW writes lane i at base+16i.
__device__ __forceinline__ void async_cp16(const unsigned short* g, unsigned short* l) {
  __builtin_amdgcn_global_load_lds(
      (const __attribute__((address_space(1))) unsigned int*)g,
      (__attribute__((address_space(3))) unsigned int*)l, 16, 0, 0);
}

// ---------------------------------------------------------------------------
__global__ void detect_dtype(const unsigned short* __restrict__ cosp, int* __restrict__ flag) {
  const int i = threadIdx.x;   // 64 threads
  const unsigned long long m = __ballot(cosp[i] >= 0x4000u);
  if (i == 0) *flag = (m != 0ull) ? 1 : 0;
}

// ---------------------------------------------------------------------------
// One-shot fp32 -> bf16 conversion of x, w_qkv, w_out (only when inputs fp32).
// ---------------------------------------------------------------------------
__global__ __launch_bounds__(256)
void cvt_all(const float* __restrict__ x, const float* __restrict__ wq,
             const float* __restrict__ wo,
             unsigned short* __restrict__ xb, unsigned short* __restrict__ wqb,
             unsigned short* __restrict__ wob, const int* __restrict__ flag) {
  if (*flag == 0) return;
  const unsigned id = blockIdx.x * 256 + threadIdx.x;  // 0..1048575
  const float* src; unsigned short* dst; unsigned off;
  if (id < 524288u) { src = x; dst = xb; off = id; }
  else if (id < 917504u) { src = wq; dst = wqb; off = id - 524288u; }
  else { src = wo; dst = wob; off = id - 917504u; }
  const float4 a = ((const float4*)src)[off * 2];
  const float4 b = ((const float4*)src)[off * 2 + 1];
  uint4 u;
  u.x = pk2(a.x, a.y); u.y = pk2(a.z, a.w);
  u.z = pk2(b.x, b.y); u.w = pk2(b.z, b.w);
  ((uint4*)dst)[off] = u;
}

// ---------------------------------------------------------------------------
// QKV projection GEMM, 128x128 tile, 512 threads / 8 waves (4M x 2N wave
// grid), BK=64, K=1024. 2-PHASE PIPELINE: LDS double-buffered (2 x 32 KB);
// STAGE(t+1) issued BEFORE compute(t) so the end-of-iteration barrier drain
// waits for loads that flew during the MFMA phase. Epilogue: RoPE (q
// pre-scaled by 0.125*log2e), per-wave 32x64 LDS transpose tile, coalesced
// uint4 scatter into q/k/v [B,H,T,64] bf16.
// ---------------------------------------------------------------------------
__global__ __launch_bounds__(512, 4)
void gemm_qkv128(const void* __restrict__ Aorig, const unsigned short* __restrict__ Aconv,
                 const void* __restrict__ Worig, const unsigned short* __restrict__ Wconv,
                 const void* __restrict__ cosp, const void* __restrict__ sinp,
                 unsigned short* __restrict__ qout,
                 unsigned short* __restrict__ kout,
                 unsigned short* __restrict__ vout,
                 const int* __restrict__ dflag) {
  const int f32flag = *dflag;
  const unsigned short* A = f32flag ? Aconv : (const unsigned short*)Aorig;
  const unsigned short* W = f32flag ? Wconv : (const unsigned short*)Worig;

  const int tid = threadIdx.x;
  const int m0 = blockIdx.y * 128;
  const int n0 = blockIdx.x * 128;

  // [buf][A(128x64) | B(128x64)] u16 -> 2 x 32 KB = 64 KB
  __shared__ __align__(16) unsigned short s_ab[2 * 16384];

  const int lane = tid & 63;
  const int wave = tid >> 6;               // 0..7
  const int wm = (wave & 3) * 32;          // wave's M offset (32 rows)
  const int wn = (wave >> 2) * 64;         // wave's N offset (64 cols = 1 head)
  const int m16 = lane & 15;
  const int quad = lane >> 4;

  const int srow = lane >> 3;
  const int schunk = (lane & 7) ^ srow;    // XOR pre-swizzle of source chunks

  const unsigned short* ga = A + (size_t)(m0 + wave * 8 + srow) * DIMC + schunk * 8;
  const unsigned short* gb = W + (size_t)(n0 + wave * 8 + srow) * DIMC + schunk * 8;

  f32x4 acc[2][4];
#pragma unroll
  for (int i = 0; i < 2; ++i)
#pragma unroll
    for (int j = 0; j < 4; ++j) acc[i][j] = (f32x4){0.f, 0.f, 0.f, 0.f};

  auto stage = [&](int b, int kt) {
    unsigned short* sa = s_ab + b * 16384;
#pragma unroll
    for (int u = 0; u < 2; ++u) {          // A and B: 128 rows each, 8 waves
      async_cp16(ga + (size_t)(u * 64) * DIMC + kt, &sa[(u * 64 + wave * 8) * 64]);
      async_cp16(gb + (size_t)(u * 64) * DIMC + kt, &sa[8192 + (u * 64 + wave * 8) * 64]);
    }
  };

  stage(0, 0);
  __syncthreads();                         // tile 0 landed

  for (int t = 0; t < 16; ++t) {
    const int cur = t & 1;
    if (t < 15) stage(cur ^ 1, (t + 1) * 64);   // issue-early: flies during MFMA
    const unsigned short* sa = s_ab + cur * 16384;
    const unsigned short* sb = sa + 8192;
    __builtin_amdgcn_s_setprio(1);
#pragma unroll
    for (int kk = 0; kk < 64; kk += 32) {
      const int cx = ((kk >> 3) + quad) ^ (m16 & 7);
      s16x8 af[2], bf[4];
#pragma unroll
      for (int i = 0; i < 2; ++i)
        af[i] = *(const s16x8*)&sa[(wm + i * 16 + m16) * 64 + cx * 8];
#pragma unroll
      for (int j = 0; j < 4; ++j)
        bf[j] = *(const s16x8*)&sb[(wn + j * 16 + m16) * 64 + cx * 8];
#pragma unroll
      for (int i = 0; i < 2; ++i)
#pragma unroll
        for (int j = 0; j < 4; ++j)
          acc[i][j] = __builtin_amdgcn_mfma_f32_16x16x32_bf16(af[i], bf[j], acc[i][j], 0, 0, 0);
    }
    __builtin_amdgcn_s_setprio(0);
    __syncthreads();                       // wait-late: drains tile t+1 loads
  }

  // Epilogue. C/D layout: col = lane&15 (within tile j), row = quad*4 + reg.
  const int sel = n0 >> 10;                // 0=q 1=k 2=v (block-uniform)
  const int h = ((n0 & 1023) >> 6) + (wave >> 2);   // wave's head
  unsigned short* dst = (sel == 0) ? qout : ((sel == 1) ? kout : vout);
  // q pre-scaled by 1/sqrt(64) * log2(e) so attention softmax is pure exp2
  const float qsc = (sel == 0) ? 0.18033688f : 1.0f;
  unsigned short* tile = s_ab + wave * 2048;   // 32x64 u16 per wave (4 KB)
  if (sel < 2) {                           // q/k: RoPE in-register
#pragma unroll
    for (int i = 0; i < 2; ++i)
#pragma unroll
      for (int r = 0; r < 4; ++r) {
        const int row_l = i * 16 + quad * 4 + r;          // 0..31
        const int t = (m0 + wm + row_l) & 2047;
#pragma unroll
        for (int jg = 0; jg < 2; ++jg) {
          const int d = jg * 16 + m16;     // head-local 0..31
          const float c = ldsc(cosp, t * 32 + d, f32flag);
          const float sn = ldsc(sinp, t * 32 + d, f32flag);
          const float v1 = acc[i][jg][r];
          const float v2 = acc[i][jg + 2][r];
          tile[row_l * 64 + d]      = f2b((v1 * c - v2 * sn) * qsc);
          tile[row_l * 64 + d + 32] = f2b((v1 * sn + v2 * c) * qsc);
        }
      }
  } else {
#pragma unroll
    for (int i = 0; i < 2; ++i)
#pragma unroll
      for (int r = 0; r < 4; ++r) {
        const int row_l = i * 16 + quad * 4 + r;
#pragma unroll
        for (int j = 0; j < 4; ++j)
          tile[row_l * 64 + j * 16 + m16] = f2b(acc[i][j][r]);
      }
  }
  // wave-private read-back: 4 coalesced uint4 stores per lane
#pragma unroll
  for (int s = 0; s < 4; ++s) {
    const int row_l = s * 8 + (lane >> 3);
    const int seg = lane & 7;
    const int mrow_ = m0 + wm + row_l;
    const int bb = mrow_ >> 11;
    const int t = mrow_ & 2047;
    unsigned short* drow = dst + (((size_t)(bb * NH + h)) * TSZ + t) * HD;
    *(uint4*)(drow + seg * 8) = *(const uint4*)&tile[row_l * 64 + seg * 8];
  }
}

// ---------------------------------------------------------------------------
// Out-projection GEMM: C[M,1024] = A[M,K] @ W[1024,K]^T. M-tile 128, N-tile
// 64, BK=64, 256 threads / 4 waves; wave owns 32x64 -> acc[2][4]. Same
// 2-phase issue-early/wait-late pipeline (LDS 2 x 24 KB). fp32 epilogue:
// per-wave 32x68-stride LDS transpose then 8 coalesced float4 stores/lane.
// ---------------------------------------------------------------------------
__global__ __launch_bounds__(256)
void gemm_out(const void* __restrict__ Aorig, const unsigned short* __restrict__ Aconv,
              const void* __restrict__ Worig, const unsigned short* __restrict__ Wconv,
              void* __restrict__ C, const int* __restrict__ dflag, int Nsz) {
  const int f32flag = *dflag;
  const unsigned short* A = f32flag ? Aconv : (const unsigned short*)Aorig;
  const unsigned short* W = f32flag ? Wconv : (const unsigned short*)Worig;

  const int tid = threadIdx.x;
  const int m0 = blockIdx.y * 128;
  const int n0 = blockIdx.x * 64;

  // [buf][A(128x64) | B(64x64)] u16 -> 2 x 24 KB = 48 KB
  __shared__ __align__(16) unsigned short s_ab[2 * 12288];

  const int lane = tid & 63;
  const int wave = tid >> 6;               // 0..3
  const int wm = wave * 32;
  const int m16 = lane & 15;
  const int quad = lane >> 4;

  const int srow = lane >> 3;
  const int schunk = (lane & 7) ^ srow;

  const unsigned short* ga = A + (size_t)(m0 + wave * 8 + srow) * DIMC + schunk * 8;
  const unsigned short* gb = W + (size_t)(n0 + wave * 8 + srow) * DIMC + schunk * 8;

  f32x4 acc[2][4];
#pragma unroll
  for (int i = 0; i < 2; ++i)
#pragma unroll
    for (int j = 0; j < 4; ++j) acc[i][j] = (f32x4){0.f, 0.f, 0.f, 0.f};

  auto stage = [&](int b, int kt) {
    unsigned short* sa = s_ab + b * 12288;
#pragma unroll
    for (int u = 0; u < 4; ++u)            // A: 128 rows, 4 waves x 8 rows
      async_cp16(ga + (size_t)(u * 32) * DIMC + kt, &sa[(u * 32 + wave * 8) * 64]);
#pragma unroll
    for (int u = 0; u < 2; ++u)            // B: 64 rows
      async_cp16(gb + (size_t)(u * 32) * DIMC + kt, &sa[8192 + (u * 32 + wave * 8) * 64]);
  };

  stage(0, 0);
  __syncthreads();

  for (int t = 0; t < 16; ++t) {
    const int cur = t & 1;
    if (t < 15) stage(cur ^ 1, (t + 1) * 64);
    const unsigned short* sa = s_ab + cur * 12288;
    const unsigned short* sb = sa + 8192;
    __builtin_amdgcn_s_setprio(1);
#pragma unroll
    for (int kk = 0; kk < 64; kk += 32) {
      const int cx = ((kk >> 3) + quad) ^ (m16 & 7);
      s16x8 af[2], bf[4];
#pragma unroll
      for (int i = 0; i < 2; ++i)
        af[i] = *(const s16x8*)&sa[(wm + i * 16 + m16) * 64 + cx * 8];
#pragma unroll
      for (int j = 0; j < 4; ++j)
        bf[j] = *(const s16x8*)&sb[(j * 16 + m16) * 64 + cx * 8];
#pragma unroll
      for (int i = 0; i < 2; ++i)
#pragma unroll
        for (int j = 0; j < 4; ++j)
          acc[i][j] = __builtin_amdgcn_mfma_f32_16x16x32_bf16(af[i], bf[j], acc[i][j], 0, 0, 0);
    }
    __builtin_amdgcn_s_setprio(0);
    __syncthreads();
  }

  // Epilogue. C/D layout: col = lane&15 (tile j), row = quad*4 + reg.
  if (f32flag) {
    float* ftile = (float*)s_ab + wave * (32 * 68);
#pragma unroll
    for (int i = 0; i < 2; ++i)
#pragma unroll
      for (int j = 0; j < 4; ++j)
#pragma unroll
        for (int r = 0; r < 4; ++r)
          ftile[(i * 16 + quad * 4 + r) * 68 + j * 16 + m16] = acc[i][j][r];
    float* Cf = (float*)C;
#pragma unroll
    for (int i = 0; i < 2; ++i)
#pragma unroll
      for (int s = 0; s < 4; ++s) {
        const int row_l = i * 16 + s * 4 + (lane >> 4);
        const float4 vv = *(const float4*)&ftile[row_l * 68 + (lane & 15) * 4];
        *(float4*)&Cf[(size_t)(m0 + wm + row_l) * Nsz + n0 + (lane & 15) * 4] = vv;
      }
  } else {
    unsigned short* Ch = (unsigned short*)C;
#pragma unroll
    for (int i = 0; i < 2; ++i)
#pragma unroll
      for (int j = 0; j < 4; ++j)
#pragma unroll
        for (int r = 0; r < 4; ++r) {
          const int mrow_ = m0 + wm + i * 16 + quad * 4 + r;
          const int col = n0 + j * 16 + m16;
          Ch[(size_t)mrow_ * Nsz + col] = f2b(acc[i][j][r]);
        }
  }
}

// ---------------------------------------------------------------------------
// MFMA flash attention, S^T form, 512 threads (8 waves), KVBLK = 128.
// Round-5 diagnosis: attn time == longest tile's serial chain (32 chunks x
// ~3630 cyc; 32*1.51us = 48.4us measured). The per-chunk cost is dominated
// by FIXED path items (barrier convergence, K lgkm wait, P LDS round-trip),
// not per-key work. KVBLK 64->128 halves the number of fixed-cost instances:
// makespan 32 -> 16 chunks, each ~1.4x -> ~0.7x total.
// Single-buffered K/V (LDS 69.6 KB, still 2 blocks/CU = the grid cap),
// 2-barrier pattern per chunk (same total barrier count as before); chunk
// k+1 prefetched into registers during compute. Front/back mirror subtile
// fusion unchanged (waves 0-3 sub p, waves 4-7 sub 31-p; co-resident pair
// durations 25 chunks, constant). Softmax in log2 domain, defer-max THR=8,
// cvt_pk packing, setprio around MFMA clusters.
// ---------------------------------------------------------------------------
__global__ __launch_bounds__(512, 4)
void attn_fwd_mfma(const unsigned short* __restrict__ qg,
                   const unsigned short* __restrict__ kg,
                   const unsigned short* __restrict__ vg,
                   unsigned short* __restrict__ outg) {
  const int tid = threadIdx.x;
  const int lane = tid & 63;
  const int w = tid >> 6;                // wave 0..7
  const int m16 = lane & 15;
  const int quad = lane >> 4;
  const int l = (int)blockIdx.x;         // 0..511
  const int g = (l & 255) >> 5;          // 0..7
  const int p = (l < 256) ? g : (15 - g);
  const int nc = (33 - p) >> 1;          // 128-key chunks for back subtile 31-p
  const int bh = l & 31;
  const int b = bh >> 4, h = bh & 15;
  const size_t base = (size_t)bh * TSZ * HD;
  // waves 0-3: front subtile p; waves 4-7: back subtile 31-p
  const int sub = (w < 4) ? p : (31 - p);
  const int qs = sub * 64 + (w & 3) * 16;   // wave's first query row

  __shared__ __align__(16) unsigned short s_k[128 * 68];   // K rows (17408 B)
  __shared__ __align__(16) unsigned short s_v[64 * 136];   // V^T (17408 B)
  __shared__ __align__(16) unsigned short s_p[128 * 136];  // P + epilogue (34816 B)

  const unsigned short* qgh = qg + base;
  const unsigned short* kgh = kg + base;
  const unsigned short* vgh = vg + base;

  const unsigned short* qrow = qgh + (size_t)(qs + m16) * HD;
  const s16x8 bq0 = *(const s16x8*)(qrow + quad * 8);
  const s16x8 bq1 = *(const s16x8*)(qrow + 32 + quad * 8);

  f32x4 oacc[4];
#pragma unroll
  for (int dt = 0; dt < 4; ++dt) oacc[dt] = (f32x4){0.f, 0.f, 0.f, 0.f};
  float m_ = -1e30f, l_ = 0.f;

  const int krow = tid >> 3, kseg = tid & 7;   // K: 2 rows/thread (r, r+64)
  const int vkey = tid & 63, vseg = tid >> 6;  // V: keys (vkey, vkey+64), 8 d

  {  // prologue: chunk 0 into LDS
    const uint4 a0 = *(const uint4*)(kgh + (size_t)krow * HD + kseg * 8);
    const uint4 a1 = *(const uint4*)(kgh + (size_t)(64 + krow) * HD + kseg * 8);
    const uint4 b0 = *(const uint4*)(vgh + (size_t)vkey * HD + vseg * 8);
    const uint4 b1 = *(const uint4*)(vgh + (size_t)(64 + vkey) * HD + vseg * 8);
    *(uint4*)&s_k[krow * 68 + kseg * 8] = a0;
    *(uint4*)&s_k[(64 + krow) * 68 + kseg * 8] = a1;
    const unsigned short* v0 = (const unsigned short*)&b0;
    const unsigned short* v1 = (const unsigned short*)&b1;
#pragma unroll
    for (int jj = 0; jj < 8; ++jj) {
      s_v[(vseg * 8 + jj) * 136 + vkey] = v0[jj];
      s_v[(vseg * 8 + jj) * 136 + 64 + vkey] = v1[jj];
    }
  }

  for (int kc = 0; kc < nc; ++kc) {
    __syncthreads();                     // chunk kc staged & visible
    uint4 a0, a1, b0, b1;
    const int pf = (kc + 1 < nc);
    if (pf) {                            // prefetch chunk kc+1 (flies in regs)
      const size_t ko = (size_t)(kc + 1) * 128;
      a0 = *(const uint4*)(kgh + (ko + krow) * HD + kseg * 8);
      a1 = *(const uint4*)(kgh + (ko + 64 + krow) * HD + kseg * 8);
      b0 = *(const uint4*)(vgh + (ko + vkey) * HD + vseg * 8);
      b1 = *(const uint4*)(vgh + (ko + 64 + vkey) * HD + vseg * 8);
    }

    if (kc * 128 <= qs + 15) {           // not fully masked for this wave
      f32x4 sacc[8];
#pragma unroll
      for (int jt = 0; jt < 8; ++jt) sacc[jt] = (f32x4){0.f, 0.f, 0.f, 0.f};
      __builtin_amdgcn_s_setprio(1);
#pragma unroll
      for (int jt = 0; jt < 8; ++jt) {
        const s16x8 ak0 = *(const s16x8*)&s_k[(jt * 16 + m16) * 68 + quad * 8];
        sacc[jt] = __builtin_amdgcn_mfma_f32_16x16x32_bf16(ak0, bq0, sacc[jt], 0, 0, 0);
        const s16x8 ak1 = *(const s16x8*)&s_k[(jt * 16 + m16) * 68 + 32 + quad * 8];
        sacc[jt] = __builtin_amdgcn_mfma_f32_16x16x32_bf16(ak1, bq1, sacc[jt], 0, 0, 0);
      }
      __builtin_amdgcn_s_setprio(0);

      if (kc * 128 + 127 > qs) {         // diagonal region: element mask
#pragma unroll
        for (int jt = 0; jt < 8; ++jt)
#pragma unroll
          for (int r = 0; r < 4; ++r)
            if (kc * 128 + jt * 16 + quad * 4 + r > qs + m16) sacc[jt][r] = -1e30f;
      }

      // per-query tile max (scores are log2-scaled)
      float mx = sacc[0][0];
#pragma unroll
      for (int jt = 0; jt < 8; ++jt)
#pragma unroll
        for (int r = 0; r < 4; ++r) mx = fmaxf(mx, sacc[jt][r]);
      mx = fmaxf(mx, __shfl_xor(mx, 16, 64));
      mx = fmaxf(mx, __shfl_xor(mx, 32, 64));
      // defer-max: rescale only when running max grew by > THR=8
      if (!__all(mx <= m_ + 8.0f)) {
        const float mn = fmaxf(m_, mx);
        const float alpha = ex2(m_ - mn);
        m_ = mn;
        l_ *= alpha;
#pragma unroll
        for (int dt = 0; dt < 4; ++dt)
#pragma unroll
          for (int r = 0; r < 4; ++r) oacc[dt][r] *= alpha;
      }
      float rs = 0.f;
#pragma unroll
      for (int jt = 0; jt < 8; ++jt)
#pragma unroll
        for (int r = 0; r < 4; ++r) {
          const float pv_ = ex2(sacc[jt][r] - m_);
          sacc[jt][r] = pv_;
          rs += pv_;
        }
      rs += __shfl_xor(rs, 16, 64);
      rs += __shfl_xor(rs, 32, 64);
      l_ += rs;

#pragma unroll
      for (int jt = 0; jt < 8; ++jt) {
        uint2 pw;
        pw.x = pk2(sacc[jt][0], sacc[jt][1]);
        pw.y = pk2(sacc[jt][2], sacc[jt][3]);
        *(uint2*)&s_p[(w * 16 + m16) * 136 + jt * 16 + quad * 4] = pw;
      }

      __builtin_amdgcn_s_setprio(1);
#pragma unroll
      for (int kk = 0; kk < 128; kk += 32) {
        const s16x8 bp = *(const s16x8*)&s_p[(w * 16 + m16) * 136 + kk + quad * 8];
#pragma unroll
        for (int dt = 0; dt < 4; ++dt) {
          const s16x8 av = *(const s16x8*)&s_v[(dt * 16 + m16) * 136 + kk + quad * 8];
          oacc[dt] = __builtin_amdgcn_mfma_f32_16x16x32_bf16(av, bp, oacc[dt], 0, 0, 0);
        }
      }
      __builtin_amdgcn_s_setprio(0);
    }

    __syncthreads();                     // all reads of chunk kc done
    if (pf) {                            // single-buffer write of chunk kc+1
      *(uint4*)&s_k[krow * 68 + kseg * 8] = a0;
      *(uint4*)&s_k[(64 + krow) * 68 + kseg * 8] = a1;
      const unsigned short* v0 = (const unsigned short*)&b0;
      const unsigned short* v1 = (const unsigned short*)&b1;
#pragma unroll
      for (int jj = 0; jj < 8; ++jj) {
        s_v[(vseg * 8 + jj) * 136 + vkey] = v0[jj];
        s_v[(vseg * 8 + jj) * 136 + 64 + vkey] = v1[jj];
      }
    }
  }

  // epilogue: normalize, transpose via wave-private s_p rows, coalesced store
  const float linv = 1.0f / l_;
#pragma unroll
  for (int dt = 0; dt < 4; ++dt) {
    uint2 ow;
    ow.x = pk2(oacc[dt][0] * linv, oacc[dt][1] * linv);
    ow.y = pk2(oacc[dt][2] * linv, oacc[dt][3] * linv);
    *(uint2*)&s_p[(w * 16 + m16) * 136 + dt * 16 + quad * 4] = ow;
  }
  {
    const int qq = lane >> 2, dseg = lane & 3;   // wave-private rows: no barrier
    const uint4 o0 = *(const uint4*)&s_p[(w * 16 + qq) * 136 + dseg * 16];
    const uint4 o1 = *(const uint4*)&s_p[(w * 16 + qq) * 136 + dseg * 16 + 8];
    unsigned short* orow =
        outg + ((size_t)b * TSZ + qs + qq) * DIMC + h * 64 + dseg * 16;
    *(uint4*)orow = o0;
    *(uint4*)(orow + 8) = o1;
  }
}

// ---------------------------------------------------------------------------
extern "C" void kernel_launch(void* const* d_in, const int* in_sizes, int n_in,
                              void* d_out, int out_size, void* d_ws, size_t ws_size,
                              hipStream_t stream) {
  (void)in_sizes; (void)n_in; (void)out_size; (void)ws_size;
  const void* x    = d_in[0];
  const void* cosp = d_in[1];
  const void* sinp = d_in[2];
  const void* wqkv = d_in[3];
  const void* wout = d_in[4];

  int* dflag = (int*)d_ws;
  const size_t per = (size_t)BSZ * NH * TSZ * HD;       // 4,194,304 elems
  unsigned short* q = (unsigned short*)((char*)d_ws + 256);
  unsigned short* k = q + per;
  unsigned short* v = k + per;
  unsigned short* attnb = v + per;                      // [B,T,DIM] bf16
  unsigned short* xb   = attnb + (size_t)MROWS * DIMC;  // bf16 copies (fp32 case)
  unsigned short* wqb  = xb + (size_t)MROWS * DIMC;
  unsigned short* wob  = wqb + (size_t)3 * DIMC * DIMC;

  detect_dtype<<<1, 64, 0, stream>>>((const unsigned short*)cosp, dflag);
  cvt_all<<<dim3(4096), dim3(256), 0, stream>>>(
      (const float*)x, (const float*)wqkv, (const float*)wout, xb, wqb, wob, dflag);
  // QKV projection: 128x128 tiles, 512 threads, 2-phase pipeline
  gemm_qkv128<<<dim3(3 * DIMC / 128, MROWS / 128), dim3(512), 0, stream>>>(
      x, xb, wqkv, wqb, cosp, sinp, q, k, v, dflag);
  // causal flash attention: 512 front/back-fused blocks, KVBLK=128
  attn_fwd_mfma<<<dim3(512), dim3(512), 0, stream>>>(q, k, v, attnb);
  // out-projection: 128x64 tiles, 2-phase pipeline + coalesced f32 epilogue
  gemm_out<<<dim3(DIMC / 64, MROWS / 128), dim3(256), 0, stream>>>(
      attnb, attnb, wout, wob, d_out, dflag, DIMC);
}